// Round 3
// baseline (359.085 us; speedup 1.0000x reference)
//
#include <hip/hip_runtime.h>
#include <hip/hip_cooperative_groups.h>

namespace cg = cooperative_groups;

typedef __bf16 bf16;
typedef bf16 bf16x8 __attribute__((ext_vector_type(8)));
typedef bf16 bf16x4 __attribute__((ext_vector_type(4)));
typedef float f32x4 __attribute__((ext_vector_type(4)));

#define EPS 1e-5f
#define SLOPE 0.01f

// async global->LDS, 16B/lane. Invariant: lds ptr == wave-uniform base + lane*16B.
__device__ __forceinline__ void gld_lds16(const bf16* g, bf16* l) {
    __builtin_amdgcn_global_load_lds(
        (const __attribute__((address_space(1))) unsigned int*)g,
        (__attribute__((address_space(3))) unsigned int*)l, 16, 0, 0);
}

// ---------- prep: xT[b][l][c], xB[b][c][l], Wk/Wv/Wo bf16, WqT[h][c][e] ------
__global__ __launch_bounds__(256) void prep_kernel(
    const float* __restrict__ x,
    const float* __restrict__ Wq, const float* __restrict__ Wk,
    const float* __restrict__ Wv, const float* __restrict__ Wo,
    bf16* __restrict__ xT, bf16* __restrict__ xB,
    bf16* __restrict__ WkB, bf16* __restrict__ WvB,
    bf16* __restrict__ WoB, bf16* __restrict__ WqT)
{
    __shared__ float tile[64][65];
    const int id = blockIdx.x;
    const int t = threadIdx.x;
    if (id < 1024) {
        const int lt = id & 15, ct = (id >> 4) & 3, b = id >> 6;
        {
            const int cl = t >> 2;            // c within tile
            const int l4 = (t & 3) << 4;      // l within tile (16-chunks)
            const float* src = x + (size_t)(b * 256 + ct * 64 + cl) * 1024 + lt * 64 + l4;
            float4 v0 = ((const float4*)src)[0];
            float4 v1 = ((const float4*)src)[1];
            float4 v2 = ((const float4*)src)[2];
            float4 v3 = ((const float4*)src)[3];
            bf16x8 r0, r1;
            r0[0]=(bf16)v0.x; r0[1]=(bf16)v0.y; r0[2]=(bf16)v0.z; r0[3]=(bf16)v0.w;
            r0[4]=(bf16)v1.x; r0[5]=(bf16)v1.y; r0[6]=(bf16)v1.z; r0[7]=(bf16)v1.w;
            r1[0]=(bf16)v2.x; r1[1]=(bf16)v2.y; r1[2]=(bf16)v2.z; r1[3]=(bf16)v2.w;
            r1[4]=(bf16)v3.x; r1[5]=(bf16)v3.y; r1[6]=(bf16)v3.z; r1[7]=(bf16)v3.w;
            bf16* xbd = xB + (size_t)(b * 256 + ct * 64 + cl) * 1024 + lt * 64 + l4;
            *(bf16x8*)xbd = r0;
            *(bf16x8*)(xbd + 8) = r1;
            float* tr = &tile[cl][l4];
            tr[0]=v0.x; tr[1]=v0.y; tr[2]=v0.z; tr[3]=v0.w;
            tr[4]=v1.x; tr[5]=v1.y; tr[6]=v1.z; tr[7]=v1.w;
            tr[8]=v2.x; tr[9]=v2.y; tr[10]=v2.z; tr[11]=v2.w;
            tr[12]=v3.x; tr[13]=v3.y; tr[14]=v3.z; tr[15]=v3.w;
        }
        __syncthreads();
        {
            const int lw = t >> 2;            // l within tile
            const int ec = (t & 3) << 4;      // c within tile
            bf16x8 o0, o1;
            #pragma unroll
            for (int ii = 0; ii < 8; ++ii) {
                o0[ii] = (bf16)tile[ec + ii][lw];
                o1[ii] = (bf16)tile[ec + 8 + ii][lw];
            }
            bf16* dst = xT + (size_t)(b * 1024 + lt * 64 + lw) * 256 + ct * 64 + ec;
            *(bf16x8*)dst = o0;
            *(bf16x8*)(dst + 8) = o1;
        }
    } else if (id < 1408) {
        // straight bf16 casts of Wk, Wv, Wo
        const int i = (id - 1024) * 1024 + t * 4;    // [0, 393216)
        const float* src; bf16* dst;
        if (i < 131072)      { src = Wk + i;            dst = WkB + i; }
        else if (i < 262144) { src = Wv + (i - 131072); dst = WvB + (i - 131072); }
        else                 { src = Wo + (i - 262144); dst = WoB + (i - 262144); }
        float4 v = *(const float4*)src;
        bf16x4 o;
        o[0]=(bf16)v.x; o[1]=(bf16)v.y; o[2]=(bf16)v.z; o[3]=(bf16)v.w;
        *(bf16x4*)dst = o;
    } else {
        // per-head transpose: WqT[h][c][e] = Wq[h*64+e][c]
        const int id2 = id - 1408;            // 0..31
        const int h = id2 >> 2, ct = id2 & 3;
        {
            const int e  = t >> 2;
            const int c4 = (t & 3) << 4;
            const float* src = Wq + (size_t)(h * 64 + e) * 256 + ct * 64 + c4;
            float4 v0 = ((const float4*)src)[0];
            float4 v1 = ((const float4*)src)[1];
            float4 v2 = ((const float4*)src)[2];
            float4 v3 = ((const float4*)src)[3];
            float* tr = &tile[e][c4];
            tr[0]=v0.x; tr[1]=v0.y; tr[2]=v0.z; tr[3]=v0.w;
            tr[4]=v1.x; tr[5]=v1.y; tr[6]=v1.z; tr[7]=v1.w;
            tr[8]=v2.x; tr[9]=v2.y; tr[10]=v2.z; tr[11]=v2.w;
            tr[12]=v3.x; tr[13]=v3.y; tr[14]=v3.z; tr[15]=v3.w;
        }
        __syncthreads();
        {
            const int c  = t >> 2;
            const int e4 = (t & 3) << 4;
            bf16x8 o0, o1;
            #pragma unroll
            for (int ii = 0; ii < 8; ++ii) {
                o0[ii] = (bf16)tile[e4 + ii][c];
                o1[ii] = (bf16)tile[e4 + 8 + ii][c];
            }
            bf16* dst = WqT + (size_t)h * 16384 + (size_t)(ct * 64 + c) * 64 + e4;
            *(bf16x8*)dst = o0;
            *(bf16x8*)(dst + 8) = o1;
        }
    }
}

// ------------------- shared-memory overlay for the mega kernel ---------------
struct __align__(16) SmG64  { bf16 As[5][64 * 32];  bf16 Bs[5][64 * 32];  };  // 40 KB
struct __align__(16) SmG128 { bf16 As[5][128 * 32]; bf16 Bs[5][128 * 32]; };  // 80 KB
struct __align__(16) SmTm   { bf16 Sc[2][8192]; bf16 Kc[2][8192];
                              bf16 Qb[16384];  bf16 Tb[4096]; };              // 104 KB
union __align__(16) SmAll { SmG64 g64; SmG128 g128; SmTm tm; };

// ------- 64x64-tile pipelined GEMM body, B^T form: C = A * Bt^T --------------
// NB=5 compile-time LDS ring, counted vmcnt, raw barrier. __syncthreads at
// entry protects LDS reuse between consecutive body calls / stages.
template<int KDIM>
__device__ __forceinline__ void gemm64_body(SmG64& s,
    const bf16* __restrict__ A, const bf16* __restrict__ Bt, bf16* __restrict__ C,
    int m0, int n0, int ldC, int t)
{
    constexpr int NT = KDIM / 32;
    constexpr int NB = 5;
    const int w = t >> 6, l = t & 63;
    const int srow = t >> 2;           // 0..63
    const int ske  = (t & 3) * 8;
    const bf16* ga = A  + (size_t)(m0 + srow) * KDIM + ske;
    const bf16* gb = Bt + (size_t)(n0 + srow) * KDIM + ske;
    const int loff = srow * 32 + ske;  // lane*16B within wave: gld_lds-safe
    const int lm = l & 15, lq = l >> 4;

    __syncthreads();                   // prior users of this LDS are done

    #pragma unroll
    for (int i = 0; i < NB - 1; ++i) {
        const int k0 = i * 32;
        gld_lds16(ga + k0, &s.As[i][0] + loff);
        gld_lds16(gb + k0, &s.Bs[i][0] + loff);
    }
    f32x4 acc[4] = {};
    #pragma unroll
    for (int kt = 0; kt < NT; ++kt) {
        const int cur = kt % NB;
        const int stg = (kt + NB - 1) % NB;
        const int remain = NT - 1 - kt;
        if (remain >= 3)      asm volatile("s_waitcnt vmcnt(6)" ::: "memory");
        else if (remain == 2) asm volatile("s_waitcnt vmcnt(4)" ::: "memory");
        else if (remain == 1) asm volatile("s_waitcnt vmcnt(2)" ::: "memory");
        else                  asm volatile("s_waitcnt vmcnt(0)" ::: "memory");
        __builtin_amdgcn_s_barrier();
        __builtin_amdgcn_sched_barrier(0);
        if (kt + NB - 1 < NT) {
            const int k0 = (kt + NB - 1) * 32;
            gld_lds16(ga + k0, &s.As[stg][0] + loff);
            gld_lds16(gb + k0, &s.Bs[stg][0] + loff);
        }
        bf16x8 af = *(const bf16x8*)(&s.As[cur][0] + (w * 16 + lm) * 32 + lq * 8);
        bf16x8 bfr[4];
        #pragma unroll
        for (int j = 0; j < 4; ++j)
            bfr[j] = *(const bf16x8*)(&s.Bs[cur][0] + (j * 16 + lm) * 32 + lq * 8);
        #pragma unroll
        for (int j = 0; j < 4; ++j)
            acc[j] = __builtin_amdgcn_mfma_f32_16x16x32_bf16(af, bfr[j], acc[j], 0, 0, 0);
    }
    #pragma unroll
    for (int j = 0; j < 4; ++j) {
        const int row = m0 + w * 16 + lq * 4;
        const int col = n0 + j * 16 + lm;
        bf16* cp = C + (size_t)row * ldC + col;
        #pragma unroll
        for (int r = 0; r < 4; ++r)
            cp[(size_t)r * ldC] = (bf16)acc[j][r];
    }
}

// ------- 128x128-tile pipelined GEMM body, B^T form --------------------------
template<int KDIM>
__device__ __forceinline__ void gemm128_body(SmG128& s,
    const bf16* __restrict__ A, const bf16* __restrict__ Bt, bf16* __restrict__ C,
    int m0, int n0, int ldC, int t)
{
    constexpr int NT = KDIM / 32;
    constexpr int NB = 5;
    const int w = t >> 6, l = t & 63;
    const int srow = w * 16 + (l >> 2);
    const int ske  = (l & 3) * 8;
    const bf16* ga = A  + (size_t)(m0 + srow) * KDIM + ske;
    const bf16* gb = Bt + (size_t)(n0 + srow) * KDIM + ske;
    const int loff = srow * 32 + ske;
    const int lm = l & 15, lq = l >> 4;
    const int wm = (w & 1) * 64, wn = (w >> 1) * 64;

    __syncthreads();

    #pragma unroll
    for (int i = 0; i < NB - 1; ++i) {
        const int k0 = i * 32;
        gld_lds16(ga + k0, &s.As[i][0] + loff);
        gld_lds16(ga + k0 + (size_t)64 * KDIM, &s.As[i][0] + 64 * 32 + loff);
        gld_lds16(gb + k0, &s.Bs[i][0] + loff);
        gld_lds16(gb + k0 + (size_t)64 * KDIM, &s.Bs[i][0] + 64 * 32 + loff);
    }
    f32x4 acc[4][4] = {};
    #pragma unroll
    for (int kt = 0; kt < NT; ++kt) {
        const int cur = kt % NB;
        const int stg = (kt + NB - 1) % NB;
        const int remain = NT - 1 - kt;
        if (remain >= 3)      asm volatile("s_waitcnt vmcnt(12)" ::: "memory");
        else if (remain == 2) asm volatile("s_waitcnt vmcnt(8)"  ::: "memory");
        else if (remain == 1) asm volatile("s_waitcnt vmcnt(4)"  ::: "memory");
        else                  asm volatile("s_waitcnt vmcnt(0)"  ::: "memory");
        __builtin_amdgcn_s_barrier();
        __builtin_amdgcn_sched_barrier(0);
        if (kt + NB - 1 < NT) {
            const int k0 = (kt + NB - 1) * 32;
            gld_lds16(ga + k0, &s.As[stg][0] + loff);
            gld_lds16(ga + k0 + (size_t)64 * KDIM, &s.As[stg][0] + 64 * 32 + loff);
            gld_lds16(gb + k0, &s.Bs[stg][0] + loff);
            gld_lds16(gb + k0 + (size_t)64 * KDIM, &s.Bs[stg][0] + 64 * 32 + loff);
        }
        bf16x8 af[4], bfr[4];
        #pragma unroll
        for (int i = 0; i < 4; ++i)
            af[i] = *(const bf16x8*)(&s.As[cur][0] + (wm + i * 16 + lm) * 32 + lq * 8);
        #pragma unroll
        for (int j = 0; j < 4; ++j)
            bfr[j] = *(const bf16x8*)(&s.Bs[cur][0] + (wn + j * 16 + lm) * 32 + lq * 8);
        #pragma unroll
        for (int i = 0; i < 4; ++i)
            #pragma unroll
            for (int j = 0; j < 4; ++j)
                acc[i][j] = __builtin_amdgcn_mfma_f32_16x16x32_bf16(af[i], bfr[j], acc[i][j], 0, 0, 0);
    }
    #pragma unroll
    for (int i = 0; i < 4; ++i)
        #pragma unroll
        for (int j = 0; j < 4; ++j) {
            const int row = m0 + wm + i * 16 + lq * 4;
            const int col = n0 + wn + j * 16 + lm;
            bf16* cp = C + (size_t)row * ldC + col;
            #pragma unroll
            for (int r = 0; r < 4; ++r)
                cp[(size_t)r * ldC] = (bf16)acc[i][j][r];
        }
}

// ---- per-(b,h): T_h = (1/64) S_h Wk_h^T  then  WmT_h = WqT_h (x) T_h --------
__device__ __forceinline__ void tm_body(SmTm& sm,
    const bf16* __restrict__ S, const bf16* __restrict__ WkB,
    const bf16* __restrict__ WqT, bf16* __restrict__ WmT, int bh, int t)
{
    const int b = bh >> 3, h = bh & 7;
    const bf16* Sg = S   + (size_t)b * 131072 + (size_t)h * 16384;
    const bf16* Kg = WkB + (size_t)h * 16384;
    const bf16* Qg = WqT + (size_t)h * 16384;
    const int w = t >> 6, l = t & 63;
    const int lm = l & 15, lq = l >> 4;

    // stage chunk0 (oldest: 8 instr), then Qb (8), then chunk1 (8)
    #pragma unroll
    for (int it = 0; it < 4; ++it) {
        const int idx = it * 256 + t;
        const int r = idx >> 4, s2 = idx & 15;
        const int gs = (s2 ^ (r & 7)) * 8;
        gld_lds16(Sg + (size_t)r * 256 + gs, &sm.Sc[0][0] + r * 128 + s2 * 8);
        gld_lds16(Kg + (size_t)r * 256 + gs, &sm.Kc[0][0] + r * 128 + s2 * 8);
    }
    #pragma unroll
    for (int it = 0; it < 8; ++it) {
        const int idx = it * 256 + t;
        const int r = idx >> 3, s2 = idx & 7;
        gld_lds16(Qg + (size_t)r * 64 + (s2 ^ (r & 7)) * 8, sm.Qb + r * 64 + s2 * 8);
    }
    #pragma unroll
    for (int it = 0; it < 4; ++it) {
        const int idx = it * 256 + t;
        const int r = idx >> 4, s2 = idx & 15;
        const int gs = (s2 ^ (r & 7)) * 8;
        gld_lds16(Sg + (size_t)r * 256 + 128 + gs, &sm.Sc[1][0] + r * 128 + s2 * 8);
        gld_lds16(Kg + (size_t)r * 256 + 128 + gs, &sm.Kc[1][0] + r * 128 + s2 * 8);
    }

    f32x4 accT[4] = {};
    // chunk0 resident (oldest 8 retired); Qb + chunk1 (16) stay in flight
    asm volatile("s_waitcnt vmcnt(16)" ::: "memory");
    __builtin_amdgcn_s_barrier();
    __builtin_amdgcn_sched_barrier(0);
    #pragma unroll
    for (int ks = 0; ks < 4; ++ks) {
        const int q = ks * 4 + lq;                 // 0..15
        const int ra = w * 16 + lm;
        bf16x8 a = *(const bf16x8*)(&sm.Sc[0][0] + ra * 128 + (q ^ (ra & 7)) * 8);
        #pragma unroll
        for (int nf = 0; nf < 4; ++nf) {
            const int rb = nf * 16 + lm;
            bf16x8 bb = *(const bf16x8*)(&sm.Kc[0][0] + rb * 128 + (q ^ (rb & 7)) * 8);
            accT[nf] = __builtin_amdgcn_mfma_f32_16x16x32_bf16(a, bb, accT[nf], 0, 0, 0);
        }
    }
    asm volatile("s_waitcnt vmcnt(0)" ::: "memory");
    __builtin_amdgcn_s_barrier();
    __builtin_amdgcn_sched_barrier(0);
    #pragma unroll
    for (int ks = 0; ks < 4; ++ks) {
        const int q = ks * 4 + lq;
        const int ra = w * 16 + lm;
        bf16x8 a = *(const bf16x8*)(&sm.Sc[1][0] + ra * 128 + (q ^ (ra & 7)) * 8);
        #pragma unroll
        for (int nf = 0; nf < 4; ++nf) {
            const int rb = nf * 16 + lm;
            bf16x8 bb = *(const bf16x8*)(&sm.Kc[1][0] + rb * 128 + (q ^ (rb & 7)) * 8);
            accT[nf] = __builtin_amdgcn_mfma_f32_16x16x32_bf16(a, bb, accT[nf], 0, 0, 0);
        }
    }
    // write T (scaled) into Tb, swizzled [64][64]
    #pragma unroll
    for (int nf = 0; nf < 4; ++nf)
        #pragma unroll
        for (int ri = 0; ri < 4; ++ri) {
            const int row = w * 16 + lq * 4 + ri;
            const int col = nf * 16 + lm;
            sm.Tb[row * 64 + (((col >> 3) ^ (row & 7)) << 3) + (col & 7)] =
                (bf16)(accT[nf][ri] * 0.015625f);
        }
    __syncthreads();

    // phase M: WmT_h[c,d] = sum_e WqT_h[c,e] T_h[d,e], M=256 N=64 K=64
    f32x4 accM[4][4] = {};
    #pragma unroll
    for (int ks = 0; ks < 2; ++ks) {
        const int q = ks * 4 + lq;                     // 0..7
        bf16x8 bfrag[4];
        #pragma unroll
        for (int nf = 0; nf < 4; ++nf) {
            const int rb = nf * 16 + lm;
            bfrag[nf] = *(const bf16x8*)(sm.Tb + rb * 64 + (q ^ (rb & 7)) * 8);
        }
        #pragma unroll
        for (int mf = 0; mf < 4; ++mf) {
            const int ra = w * 64 + mf * 16 + lm;
            bf16x8 a = *(const bf16x8*)(sm.Qb + ra * 64 + (q ^ (ra & 7)) * 8);
            #pragma unroll
            for (int nf = 0; nf < 4; ++nf)
                accM[mf][nf] = __builtin_amdgcn_mfma_f32_16x16x32_bf16(a, bfrag[nf], accM[mf][nf], 0, 0, 0);
        }
    }
    bf16* Wg = WmT + (size_t)b * 131072 + h * 64;
    #pragma unroll
    for (int mf = 0; mf < 4; ++mf)
        #pragma unroll
        for (int nf = 0; nf < 4; ++nf)
            #pragma unroll
            for (int ri = 0; ri < 4; ++ri) {
                const int c = w * 64 + mf * 16 + lq * 4 + ri;
                const int d = nf * 16 + lm;
                Wg[(size_t)c * 512 + d] = (bf16)accM[mf][nf][ri];
            }
}

// ---------------- cooperative mega-kernel: G -> S -> tm -> Wt -> o -----------
// 256 blocks x 256 threads, 104 KB LDS -> exactly 1 block/CU (coop-resident).
__global__ __launch_bounds__(256) void mega_kernel(
    const bf16* __restrict__ xB, const bf16* __restrict__ xT,
    const bf16* __restrict__ WkB, const bf16* __restrict__ WvB,
    const bf16* __restrict__ WoB, const bf16* __restrict__ WqT,
    bf16* __restrict__ G, bf16* __restrict__ S, bf16* __restrict__ WmT,
    bf16* __restrict__ Wt, bf16* __restrict__ o)
{
    __shared__ SmAll sm;
    cg::grid_group grid = cg::this_grid();
    const int t = threadIdx.x;
    const int bid = blockIdx.x;

    // Stage G: G[z] = xB[z] (x) xB[z]^T, [256,256] K=1024, 256 x 64x64 tiles
    {
        const int z = bid >> 4, mx = (bid >> 2) & 3, my = bid & 3;
        gemm64_body<1024>(sm.g64, xB + (size_t)z * 262144, xB + (size_t)z * 262144,
                          G + (size_t)z * 65536, mx * 64, my * 64, 256, t);
    }
    __threadfence(); grid.sync();

    // Stage S: S[z] = WvB (x) G[z]^T, [512,256] K=256, 512 tiles -> 2/block
    for (int i = 0; i < 2; ++i) {
        const int tid = i * 256 + bid;
        const int z = tid >> 5, mx = (tid >> 2) & 7, my = tid & 3;
        gemm64_body<256>(sm.g64, WvB, G + (size_t)z * 65536,
                         S + (size_t)z * 131072, mx * 64, my * 64, 256, t);
    }
    __threadfence(); grid.sync();

    // Stage tm: blocks 0..127 (one per (b,h))
    if (bid < 128) tm_body(sm.tm, S, WkB, WqT, WmT, bid, t);
    __threadfence(); grid.sync();

    // Stage Wt: Wt[z] = WoB (x) WmT[z]^T, [256,256] K=512, 256 tiles
    {
        const int z = bid >> 4, mx = (bid >> 2) & 3, my = bid & 3;
        gemm64_body<512>(sm.g64, WoB, WmT + (size_t)z * 131072,
                         Wt + (size_t)z * 65536, mx * 64, my * 64, 256, t);
    }
    __threadfence(); grid.sync();

    // Stage o: o[z] = Wt[z] (x) xT[z]^T, [256,1024] K=256, 256 x 128x128 tiles
    {
        const int z = bid >> 4, mx = (bid >> 3) & 1, my = bid & 7;
        gemm128_body<256>(sm.g128, Wt + (size_t)z * 65536, xT + (size_t)z * 262144,
                          o + (size_t)z * 262144, mx * 128, my * 128, 1024, t);
    }
}

// ------------- InstanceNorm over L + gamma residual + LeakyReLU --------------
__global__ __launch_bounds__(256) void norm_kernel(
    const bf16* __restrict__ o, const bf16* __restrict__ xB,
    const float* __restrict__ gamma, float* __restrict__ y)
{
    const size_t row = blockIdx.x;
    const bf16* orow = o + row * 1024;
    const bf16* xrow = xB + row * 1024;
    float* yrow = y + row * 1024;
    const int tid = threadIdx.x;

    bf16x4 ov = *(const bf16x4*)(orow + tid * 4);
    float4 v = {(float)ov[0], (float)ov[1], (float)ov[2], (float)ov[3]};
    float s  = v.x + v.y + v.z + v.w;
    float ss = v.x * v.x + v.y * v.y + v.z * v.z + v.w * v.w;
    #pragma unroll
    for (int off = 32; off > 0; off >>= 1) {
        s  += __shfl_down(s, off);
        ss += __shfl_down(ss, off);
    }
    __shared__ float red[10];
    const int wave = tid >> 6, lane = tid & 63;
    if (lane == 0) { red[wave] = s; red[4 + wave] = ss; }
    __syncthreads();
    if (tid == 0) {
        float a  = red[0] + red[1] + red[2] + red[3];
        float b2 = red[4] + red[5] + red[6] + red[7];
        float mu = a * (1.0f / 1024.0f);
        float var = b2 * (1.0f / 1024.0f) - mu * mu;
        red[8] = mu;
        red[9] = rsqrtf(var + EPS);
    }
    __syncthreads();
    const float mu = red[8], inv = red[9], g = gamma[0];
    bf16x4 xv4 = *(const bf16x4*)(xrow + tid * 4);
    float4 r;
    r.x = (v.x - mu) * inv * g + (float)xv4[0];
    r.y = (v.y - mu) * inv * g + (float)xv4[1];
    r.z = (v.z - mu) * inv * g + (float)xv4[2];
    r.w = (v.w - mu) * inv * g + (float)xv4[3];
    r.x = r.x >= 0.f ? r.x : SLOPE * r.x;
    r.y = r.y >= 0.f ? r.y : SLOPE * r.y;
    r.z = r.z >= 0.f ? r.z : SLOPE * r.z;
    r.w = r.w >= 0.f ? r.w : SLOPE * r.w;
    ((float4*)yrow)[tid] = r;
}

extern "C" void kernel_launch(void* const* d_in, const int* in_sizes, int n_in,
                              void* d_out, int out_size, void* d_ws, size_t ws_size,
                              hipStream_t stream) {
    const float* x     = (const float*)d_in[0];
    const float* Wq    = (const float*)d_in[1];
    const float* Wk    = (const float*)d_in[2];
    const float* Wv    = (const float*)d_in[3];
    const float* Wo    = (const float*)d_in[4];
    const float* gamma = (const float*)d_in[5];
    float* y = (float*)d_out;

    char* wsb = (char*)d_ws;
    bf16* xT  = (bf16*)(wsb);                   //  8,388,608
    bf16* xB  = (bf16*)(wsb +  8388608);        //  8,388,608
    bf16* WkB = (bf16*)(wsb + 16777216);        //    262,144
    bf16* WvB = (bf16*)(wsb + 17039360);        //    262,144
    bf16* WoB = (bf16*)(wsb + 17301504);        //    262,144
    bf16* WqT = (bf16*)(wsb + 17563648);        //    262,144
    bf16* G   = (bf16*)(wsb + 17825792);        //  2,097,152
    bf16* S   = (bf16*)(wsb + 19922944);        //  4,194,304
    bf16* WmT = (bf16*)(wsb + 24117248);        //  4,194,304
    bf16* Wt  = (bf16*)(wsb + 28311552);        //  2,097,152
    bf16* o   = (bf16*)(wsb + 30408704);        //  8,388,608  (end 38,797,312)

    prep_kernel<<<dim3(1440), 256, 0, stream>>>(x, Wq, Wk, Wv, Wo, xT, xB, WkB, WvB, WoB, WqT);

    // cooperative mega-kernel: G -> S -> tm -> Wt -> o (4 grid syncs)
    const bf16* xBa = xB;  const bf16* xTa = xT;
    const bf16* WkBa = WkB; const bf16* WvBa = WvB;
    const bf16* WoBa = WoB; const bf16* WqTa = WqT;
    bf16* Ga = G; bf16* Sa = S; bf16* WmTa = WmT; bf16* Wta = Wt; bf16* oa = o;
    void* margs[] = { &xBa, &xTa, &WkBa, &WvBa, &WoBa, &WqTa,
                      &Ga, &Sa, &WmTa, &Wta, &oa };
    hipLaunchCooperativeKernel((const void*)mega_kernel, dim3(256), dim3(256),
                               margs, 0, stream);

    norm_kernel<<<dim3(4096), 256, 0, stream>>>(o, xB, gamma, y);
}

// Round 4
// 122.687 us; speedup vs baseline: 2.9268x; 2.9268x over previous
//
#include <hip/hip_runtime.h>

typedef __bf16 bf16;
typedef bf16 bf16x8 __attribute__((ext_vector_type(8)));
typedef bf16 bf16x4 __attribute__((ext_vector_type(4)));
typedef float f32x4 __attribute__((ext_vector_type(4)));

#define EPS 1e-5f
#define SLOPE 0.01f

// async global->LDS, 16B/lane. Invariant: lds ptr == wave-uniform base + lane*16B.
__device__ __forceinline__ void gld_lds16(const bf16* g, bf16* l) {
    __builtin_amdgcn_global_load_lds(
        (const __attribute__((address_space(1))) unsigned int*)g,
        (__attribute__((address_space(3))) unsigned int*)l, 16, 0, 0);
}

// ---------- prep: xT[b][l][c], xB[b][c][l], Wk/Wv/Wo bf16, WqT[h][c][e] ------
__global__ __launch_bounds__(256) void prep_kernel(
    const float* __restrict__ x,
    const float* __restrict__ Wq, const float* __restrict__ Wk,
    const float* __restrict__ Wv, const float* __restrict__ Wo,
    bf16* __restrict__ xT, bf16* __restrict__ xB,
    bf16* __restrict__ WkB, bf16* __restrict__ WvB,
    bf16* __restrict__ WoB, bf16* __restrict__ WqT)
{
    __shared__ float tile[64][65];
    const int id = blockIdx.x;
    const int t = threadIdx.x;
    if (id < 1024) {
        const int lt = id & 15, ct = (id >> 4) & 3, b = id >> 6;
        {
            const int cl = t >> 2;            // c within tile
            const int l4 = (t & 3) << 4;      // l within tile (16-chunks)
            const float* src = x + (size_t)(b * 256 + ct * 64 + cl) * 1024 + lt * 64 + l4;
            float4 v0 = ((const float4*)src)[0];
            float4 v1 = ((const float4*)src)[1];
            float4 v2 = ((const float4*)src)[2];
            float4 v3 = ((const float4*)src)[3];
            bf16x8 r0, r1;
            r0[0]=(bf16)v0.x; r0[1]=(bf16)v0.y; r0[2]=(bf16)v0.z; r0[3]=(bf16)v0.w;
            r0[4]=(bf16)v1.x; r0[5]=(bf16)v1.y; r0[6]=(bf16)v1.z; r0[7]=(bf16)v1.w;
            r1[0]=(bf16)v2.x; r1[1]=(bf16)v2.y; r1[2]=(bf16)v2.z; r1[3]=(bf16)v2.w;
            r1[4]=(bf16)v3.x; r1[5]=(bf16)v3.y; r1[6]=(bf16)v3.z; r1[7]=(bf16)v3.w;
            bf16* xbd = xB + (size_t)(b * 256 + ct * 64 + cl) * 1024 + lt * 64 + l4;
            *(bf16x8*)xbd = r0;
            *(bf16x8*)(xbd + 8) = r1;
            float* tr = &tile[cl][l4];
            tr[0]=v0.x; tr[1]=v0.y; tr[2]=v0.z; tr[3]=v0.w;
            tr[4]=v1.x; tr[5]=v1.y; tr[6]=v1.z; tr[7]=v1.w;
            tr[8]=v2.x; tr[9]=v2.y; tr[10]=v2.z; tr[11]=v2.w;
            tr[12]=v3.x; tr[13]=v3.y; tr[14]=v3.z; tr[15]=v3.w;
        }
        __syncthreads();
        {
            const int lw = t >> 2;            // l within tile
            const int ec = (t & 3) << 4;      // c within tile
            bf16x8 o0, o1;
            #pragma unroll
            for (int ii = 0; ii < 8; ++ii) {
                o0[ii] = (bf16)tile[ec + ii][lw];
                o1[ii] = (bf16)tile[ec + 8 + ii][lw];
            }
            bf16* dst = xT + (size_t)(b * 1024 + lt * 64 + lw) * 256 + ct * 64 + ec;
            *(bf16x8*)dst = o0;
            *(bf16x8*)(dst + 8) = o1;
        }
    } else if (id < 1408) {
        // straight bf16 casts of Wk, Wv, Wo
        const int i = (id - 1024) * 1024 + t * 4;    // [0, 393216)
        const float* src; bf16* dst;
        if (i < 131072)      { src = Wk + i;            dst = WkB + i; }
        else if (i < 262144) { src = Wv + (i - 131072); dst = WvB + (i - 131072); }
        else                 { src = Wo + (i - 262144); dst = WoB + (i - 262144); }
        float4 v = *(const float4*)src;
        bf16x4 o;
        o[0]=(bf16)v.x; o[1]=(bf16)v.y; o[2]=(bf16)v.z; o[3]=(bf16)v.w;
        *(bf16x4*)dst = o;
    } else {
        // per-head transpose: WqT[h][c][e] = Wq[h*64+e][c]
        const int id2 = id - 1408;            // 0..31
        const int h = id2 >> 2, ct = id2 & 3;
        {
            const int e  = t >> 2;
            const int c4 = (t & 3) << 4;
            const float* src = Wq + (size_t)(h * 64 + e) * 256 + ct * 64 + c4;
            float4 v0 = ((const float4*)src)[0];
            float4 v1 = ((const float4*)src)[1];
            float4 v2 = ((const float4*)src)[2];
            float4 v3 = ((const float4*)src)[3];
            float* tr = &tile[e][c4];
            tr[0]=v0.x; tr[1]=v0.y; tr[2]=v0.z; tr[3]=v0.w;
            tr[4]=v1.x; tr[5]=v1.y; tr[6]=v1.z; tr[7]=v1.w;
            tr[8]=v2.x; tr[9]=v2.y; tr[10]=v2.z; tr[11]=v2.w;
            tr[12]=v3.x; tr[13]=v3.y; tr[14]=v3.z; tr[15]=v3.w;
        }
        __syncthreads();
        {
            const int c  = t >> 2;
            const int e4 = (t & 3) << 4;
            bf16x8 o0, o1;
            #pragma unroll
            for (int ii = 0; ii < 8; ++ii) {
                o0[ii] = (bf16)tile[e4 + ii][c];
                o1[ii] = (bf16)tile[e4 + 8 + ii][c];
            }
            bf16* dst = WqT + (size_t)h * 16384 + (size_t)(ct * 64 + c) * 64 + e4;
            *(bf16x8*)dst = o0;
            *(bf16x8*)(dst + 8) = o1;
        }
    }
}

// ------- 128x128-tile MFMA GEMM, B^T form: C[z] = A[z] * Bt[z]^T -------------
// NB=5 LDS ring, fully unrolled (compile-time ring indices), counted vmcnt.
template<int KDIM, typename OutT>
__global__ __launch_bounds__(256) void gemm128_bt(
    const bf16* __restrict__ A, const bf16* __restrict__ Bt, OutT* __restrict__ C,
    long long sA, long long sBt, long long sC, int ldC)
{
    constexpr int NT = KDIM / 32;      // K-tiles
    constexpr int NB = 5;              // LDS ring depth (4 tiles in flight)
    __shared__ bf16 As[NB][128 * 32];  // 40 KB
    __shared__ bf16 Bs[NB][128 * 32];  // 40 KB
    const int z = blockIdx.z;
    A  += (size_t)z * sA;
    Bt += (size_t)z * sBt;
    C  += (size_t)z * sC;
    const int m0 = blockIdx.x * 128;
    const int n0 = blockIdx.y * 128;
    const int t = threadIdx.x, w = t >> 6, l = t & 63;
    const int srow = w * 16 + (l >> 2);
    const int ske  = (l & 3) * 8;
    const bf16* ga = A  + (size_t)(m0 + srow) * KDIM + ske;
    const bf16* gb = Bt + (size_t)(n0 + srow) * KDIM + ske;
    const int loff = srow * 32 + ske;  // lane*16B within wave: gld_lds-safe
    const int lm = l & 15, lq = l >> 4;
    const int wm = (w & 1) * 64, wn = (w >> 1) * 64;

    #pragma unroll
    for (int i = 0; i < NB - 1; ++i) {
        const int k0 = i * 32;
        gld_lds16(ga + k0, &As[i][0] + loff);
        gld_lds16(ga + k0 + (size_t)64 * KDIM, &As[i][0] + 64 * 32 + loff);
        gld_lds16(gb + k0, &Bs[i][0] + loff);
        gld_lds16(gb + k0 + (size_t)64 * KDIM, &Bs[i][0] + 64 * 32 + loff);
    }

    f32x4 acc[4][4] = {};
    #pragma unroll
    for (int kt = 0; kt < NT; ++kt) {
        const int cur = kt % NB;
        const int stg = (kt + NB - 1) % NB;
        const int remain = NT - 1 - kt;
        if (remain >= 3)      asm volatile("s_waitcnt vmcnt(12)" ::: "memory");
        else if (remain == 2) asm volatile("s_waitcnt vmcnt(8)"  ::: "memory");
        else if (remain == 1) asm volatile("s_waitcnt vmcnt(4)"  ::: "memory");
        else                  asm volatile("s_waitcnt vmcnt(0)"  ::: "memory");
        __builtin_amdgcn_s_barrier();
        __builtin_amdgcn_sched_barrier(0);
        if (kt + NB - 1 < NT) {
            const int k0 = (kt + NB - 1) * 32;
            gld_lds16(ga + k0, &As[stg][0] + loff);
            gld_lds16(ga + k0 + (size_t)64 * KDIM, &As[stg][0] + 64 * 32 + loff);
            gld_lds16(gb + k0, &Bs[stg][0] + loff);
            gld_lds16(gb + k0 + (size_t)64 * KDIM, &Bs[stg][0] + 64 * 32 + loff);
        }
        bf16x8 af[4], bfr[4];
        #pragma unroll
        for (int i = 0; i < 4; ++i)
            af[i] = *(const bf16x8*)(&As[cur][0] + (wm + i * 16 + lm) * 32 + lq * 8);
        #pragma unroll
        for (int j = 0; j < 4; ++j)
            bfr[j] = *(const bf16x8*)(&Bs[cur][0] + (wn + j * 16 + lm) * 32 + lq * 8);
        #pragma unroll
        for (int i = 0; i < 4; ++i)
            #pragma unroll
            for (int j = 0; j < 4; ++j)
                acc[i][j] = __builtin_amdgcn_mfma_f32_16x16x32_bf16(af[i], bfr[j], acc[i][j], 0, 0, 0);
    }
    #pragma unroll
    for (int i = 0; i < 4; ++i)
        #pragma unroll
        for (int j = 0; j < 4; ++j) {
            const int row = m0 + wm + i * 16 + lq * 4;
            const int col = n0 + wn + j * 16 + lm;
            OutT* cp = C + (size_t)row * ldC + col;
            #pragma unroll
            for (int r = 0; r < 4; ++r)
                cp[(size_t)r * ldC] = (OutT)acc[i][j][r];
        }
}

// ------- 64x64-tile MFMA GEMM, B^T form ------------
template<int KDIM, typename OutT>
__global__ __launch_bounds__(256) void gemm64_bt(
    const bf16* __restrict__ A, const bf16* __restrict__ Bt, OutT* __restrict__ C,
    long long sA, long long sBt, long long sC, int ldC)
{
    constexpr int NT = KDIM / 32;
    constexpr int NB = 5;
    __shared__ bf16 As[NB][64 * 32];   // 20 KB
    __shared__ bf16 Bs[NB][64 * 32];   // 20 KB
    const int z = blockIdx.z;
    A  += (size_t)z * sA;
    Bt += (size_t)z * sBt;
    C  += (size_t)z * sC;
    const int m0 = blockIdx.x * 64;
    const int n0 = blockIdx.y * 64;
    const int t = threadIdx.x, w = t >> 6, l = t & 63;
    const int srow = t >> 2;           // 0..63
    const int ske  = (t & 3) * 8;
    const bf16* ga = A  + (size_t)(m0 + srow) * KDIM + ske;
    const bf16* gb = Bt + (size_t)(n0 + srow) * KDIM + ske;
    const int loff = srow * 32 + ske;
    const int lm = l & 15, lq = l >> 4;

    #pragma unroll
    for (int i = 0; i < NB - 1; ++i) {
        const int k0 = i * 32;
        gld_lds16(ga + k0, &As[i][0] + loff);
        gld_lds16(gb + k0, &Bs[i][0] + loff);
    }

    f32x4 acc[4] = {};
    #pragma unroll
    for (int kt = 0; kt < NT; ++kt) {
        const int cur = kt % NB;
        const int stg = (kt + NB - 1) % NB;
        const int remain = NT - 1 - kt;
        if (remain >= 3)      asm volatile("s_waitcnt vmcnt(6)" ::: "memory");
        else if (remain == 2) asm volatile("s_waitcnt vmcnt(4)" ::: "memory");
        else if (remain == 1) asm volatile("s_waitcnt vmcnt(2)" ::: "memory");
        else                  asm volatile("s_waitcnt vmcnt(0)" ::: "memory");
        __builtin_amdgcn_s_barrier();
        __builtin_amdgcn_sched_barrier(0);
        if (kt + NB - 1 < NT) {
            const int k0 = (kt + NB - 1) * 32;
            gld_lds16(ga + k0, &As[stg][0] + loff);
            gld_lds16(gb + k0, &Bs[stg][0] + loff);
        }
        bf16x8 af = *(const bf16x8*)(&As[cur][0] + (w * 16 + lm) * 32 + lq * 8);
        bf16x8 bfr[4];
        #pragma unroll
        for (int j = 0; j < 4; ++j)
            bfr[j] = *(const bf16x8*)(&Bs[cur][0] + (j * 16 + lm) * 32 + lq * 8);
        #pragma unroll
        for (int j = 0; j < 4; ++j)
            acc[j] = __builtin_amdgcn_mfma_f32_16x16x32_bf16(af, bfr[j], acc[j], 0, 0, 0);
    }
    #pragma unroll
    for (int j = 0; j < 4; ++j) {
        const int row = m0 + w * 16 + lq * 4;
        const int col = n0 + j * 16 + lm;
        OutT* cp = C + (size_t)row * ldC + col;
        #pragma unroll
        for (int r = 0; r < 4; ++r)
            cp[(size_t)r * ldC] = (OutT)acc[j][r];
    }
}

// ---- tm2 per (b,h): P = Wv_h (x) G_b (=S_h), T = (1/64) P Wk_h^T,
//      WmT_h = WqT_h (x) T_h.  S never touches global memory.
// LDS union (128 KB): phase P: {P, Va, Gr[4-ring]}; phase T/M: {P, Kc, Qb, Tb}.
struct __align__(16) Tm2Ph1 { bf16 P[16384]; bf16 Va[16384]; bf16 Gr[4][8192]; };
struct __align__(16) Tm2Ph2 { bf16 P[16384]; bf16 Kc[16384]; bf16 Qb[16384]; bf16 Tb[4096]; };
union  __align__(16) Tm2Sm  { Tm2Ph1 p1; Tm2Ph2 p2; };   // 128 KB, P aliases P

__global__ __launch_bounds__(256) void tm2_kernel(
    const bf16* __restrict__ G, const bf16* __restrict__ WvB,
    const bf16* __restrict__ WkB, const bf16* __restrict__ WqT,
    bf16* __restrict__ WmT)
{
    __shared__ Tm2Sm sm;
    const int bh = blockIdx.x;
    const int b = bh >> 3, h = bh & 7;
    const bf16* Gg = G   + (size_t)b * 65536;       // [256][256]
    const bf16* Vg = WvB + (size_t)h * 16384;       // Wv_h [64][256]
    const bf16* Kg = WkB + (size_t)h * 16384;       // Wk_h [64][256]
    const bf16* Qg = WqT + (size_t)h * 16384;       // WqT_h [256][64]
    const int t = threadIdx.x, w = t >> 6, l = t & 63;
    const int lm = l & 15, lq = l >> 4;

    // ---- phase P staging: Gr t0, Va, Gr t1, Gr t2 (20 gld/thread) ----
    // Gr tile: [256 rows][4 segs of 8], swizzle seg^(row&3), pre-swizzled src.
    // Va: [64 rows][32 segs of 8], swizzle seg^(row&7).
    {
        const int rb = t >> 2 << 2;  // unused placeholder (kept simple below)
    }
    #pragma unroll
    for (int it = 0; it < 4; ++it) {               // tile 0
        const int idx = it * 256 + t;
        const int r = idx >> 2, s2 = idx & 3;
        gld_lds16(Gg + (size_t)r * 256 + 0 * 32 + (s2 ^ (r & 3)) * 8,
                  &sm.p1.Gr[0][0] + r * 32 + s2 * 8);
    }
    #pragma unroll
    for (int it = 0; it < 8; ++it) {               // Va
        const int idx = it * 256 + t;
        const int r = idx >> 5, s = idx & 31;
        gld_lds16(Vg + (size_t)r * 256 + (s ^ (r & 7)) * 8,
                  sm.p1.Va + r * 256 + s * 8);
    }
    #pragma unroll
    for (int tb = 1; tb < 3; ++tb) {               // tiles 1,2
        #pragma unroll
        for (int it = 0; it < 4; ++it) {
            const int idx = it * 256 + t;
            const int r = idx >> 2, s2 = idx & 3;
            gld_lds16(Gg + (size_t)r * 256 + tb * 32 + (s2 ^ (r & 3)) * 8,
                      &sm.p1.Gr[tb][0] + r * 32 + s2 * 8);
        }
    }

    // ---- phase P K-loop: P[d][c] = sum_k Wv[d,k] G[c,k], M=64 N=256 K=256 ---
    // wave w owns cols w*64..w*64+63; acc[mf][nf] = 4 m-frags x 4 n-frags.
    f32x4 accP[4][4] = {};
    #pragma unroll
    for (int kt = 0; kt < 8; ++kt) {
        if (kt <= 5)      asm volatile("s_waitcnt vmcnt(8)" ::: "memory");
        else if (kt == 6) asm volatile("s_waitcnt vmcnt(4)" ::: "memory");
        else              asm volatile("s_waitcnt vmcnt(0)" ::: "memory");
        __builtin_amdgcn_s_barrier();
        __builtin_amdgcn_sched_barrier(0);
        if (kt < 5) {                               // stage tile kt+3
            const int tb = kt + 3;
            #pragma unroll
            for (int it = 0; it < 4; ++it) {
                const int idx = it * 256 + t;
                const int r = idx >> 2, s2 = idx & 3;
                gld_lds16(Gg + (size_t)r * 256 + tb * 32 + (s2 ^ (r & 3)) * 8,
                          &sm.p1.Gr[tb & 3][0] + r * 32 + s2 * 8);
            }
        }
        bf16x8 af[4], bfr[4];
        #pragma unroll
        for (int mf = 0; mf < 4; ++mf) {
            const int ra = mf * 16 + lm;
            af[mf] = *(const bf16x8*)(sm.p1.Va + ra * 256 + ((kt * 4 + lq) ^ (ra & 7)) * 8);
        }
        #pragma unroll
        for (int nf = 0; nf < 4; ++nf) {
            const int rb = w * 64 + nf * 16 + lm;
            bfr[nf] = *(const bf16x8*)(&sm.p1.Gr[kt & 3][0] + rb * 32 + (lq ^ (rb & 3)) * 8);
        }
        #pragma unroll
        for (int mf = 0; mf < 4; ++mf)
            #pragma unroll
            for (int nf = 0; nf < 4; ++nf)
                accP[mf][nf] = __builtin_amdgcn_mfma_f32_16x16x32_bf16(af[mf], bfr[nf], accP[mf][nf], 0, 0, 0);
    }
    // write P (bf16, unscaled - matches old S rounding) swizzled [64][256]
    #pragma unroll
    for (int mf = 0; mf < 4; ++mf)
        #pragma unroll
        for (int nf = 0; nf < 4; ++nf)
            #pragma unroll
            for (int ri = 0; ri < 4; ++ri) {
                const int d = mf * 16 + lq * 4 + ri;
                const int c = w * 64 + nf * 16 + lm;
                sm.p1.P[d * 256 + (((c >> 3) ^ (d & 7)) << 3) + (c & 7)] =
                    (bf16)accP[mf][nf][ri];
            }
    __syncthreads();   // all waves done with Va/Gr; P published

    // ---- stage Kc (aliases Va) and Qb (aliases Gr) ----
    #pragma unroll
    for (int it = 0; it < 8; ++it) {
        const int idx = it * 256 + t;
        const int r = idx >> 5, s = idx & 31;
        gld_lds16(Kg + (size_t)r * 256 + (s ^ (r & 7)) * 8,
                  sm.p2.Kc + r * 256 + s * 8);
    }
    #pragma unroll
    for (int it = 0; it < 8; ++it) {
        const int idx = it * 256 + t;
        const int r = idx >> 3, s2 = idx & 7;
        gld_lds16(Qg + (size_t)r * 64 + (s2 ^ (r & 7)) * 8,
                  sm.p2.Qb + r * 64 + s2 * 8);
    }

    // ---- phase T: T[d][e] = (1/64) sum_c P[d,c] Wk[e,c], M=64 N=64 K=256 ----
    asm volatile("s_waitcnt vmcnt(8)" ::: "memory");   // Kc resident, Qb in flight
    __builtin_amdgcn_s_barrier();
    __builtin_amdgcn_sched_barrier(0);
    f32x4 accT[4] = {};
    #pragma unroll
    for (int kk = 0; kk < 8; ++kk) {
        const int ra = w * 16 + lm;
        bf16x8 a = *(const bf16x8*)(sm.p2.P + ra * 256 + ((kk * 4 + lq) ^ (ra & 7)) * 8);
        #pragma unroll
        for (int nf = 0; nf < 4; ++nf) {
            const int rb = nf * 16 + lm;
            bf16x8 bb = *(const bf16x8*)(sm.p2.Kc + rb * 256 + ((kk * 4 + lq) ^ (rb & 7)) * 8);
            accT[nf] = __builtin_amdgcn_mfma_f32_16x16x32_bf16(a, bb, accT[nf], 0, 0, 0);
        }
    }
    // write T (scaled 1/64) into Tb, swizzled [64][64]
    #pragma unroll
    for (int nf = 0; nf < 4; ++nf)
        #pragma unroll
        for (int ri = 0; ri < 4; ++ri) {
            const int row = w * 16 + lq * 4 + ri;
            const int col = nf * 16 + lm;
            sm.p2.Tb[row * 64 + (((col >> 3) ^ (row & 7)) << 3) + (col & 7)] =
                (bf16)(accT[nf][ri] * 0.015625f);
        }
    asm volatile("s_waitcnt vmcnt(0)" ::: "memory");   // Qb resident
    __syncthreads();                                   // Tb + Qb published

    // ---- phase M: WmT_h[c,d] = sum_e WqT_h[c,e] T_h[d,e], M=256 N=64 K=64 ---
    f32x4 accM[4][4] = {};
    #pragma unroll
    for (int ks = 0; ks < 2; ++ks) {
        const int q = ks * 4 + lq;                     // 0..7
        bf16x8 bfrag[4];
        #pragma unroll
        for (int nf = 0; nf < 4; ++nf) {
            const int rb = nf * 16 + lm;
            bfrag[nf] = *(const bf16x8*)(sm.p2.Tb + rb * 64 + (q ^ (rb & 7)) * 8);
        }
        #pragma unroll
        for (int mf = 0; mf < 4; ++mf) {
            const int ra = w * 64 + mf * 16 + lm;
            bf16x8 a = *(const bf16x8*)(sm.p2.Qb + ra * 64 + (q ^ (ra & 7)) * 8);
            #pragma unroll
            for (int nf = 0; nf < 4; ++nf)
                accM[mf][nf] = __builtin_amdgcn_mfma_f32_16x16x32_bf16(a, bfrag[nf], accM[mf][nf], 0, 0, 0);
        }
    }
    bf16* Wg = WmT + (size_t)b * 131072 + h * 64;
    #pragma unroll
    for (int mf = 0; mf < 4; ++mf)
        #pragma unroll
        for (int nf = 0; nf < 4; ++nf)
            #pragma unroll
            for (int ri = 0; ri < 4; ++ri) {
                const int c = w * 64 + mf * 16 + lq * 4 + ri;
                const int d = nf * 16 + lm;
                Wg[(size_t)c * 512 + d] = (bf16)accM[mf][nf][ri];
            }
}

// ------------- InstanceNorm over L + gamma residual + LeakyReLU --------------
__global__ __launch_bounds__(256) void norm_kernel(
    const bf16* __restrict__ o, const bf16* __restrict__ xB,
    const float* __restrict__ gamma, float* __restrict__ y)
{
    const size_t row = blockIdx.x;
    const bf16* orow = o + row * 1024;
    const bf16* xrow = xB + row * 1024;
    float* yrow = y + row * 1024;
    const int tid = threadIdx.x;

    bf16x4 ov = *(const bf16x4*)(orow + tid * 4);
    float4 v = {(float)ov[0], (float)ov[1], (float)ov[2], (float)ov[3]};
    float s  = v.x + v.y + v.z + v.w;
    float ss = v.x * v.x + v.y * v.y + v.z * v.z + v.w * v.w;
    #pragma unroll
    for (int off = 32; off > 0; off >>= 1) {
        s  += __shfl_down(s, off);
        ss += __shfl_down(ss, off);
    }
    __shared__ float red[10];
    const int wave = tid >> 6, lane = tid & 63;
    if (lane == 0) { red[wave] = s; red[4 + wave] = ss; }
    __syncthreads();
    if (tid == 0) {
        float a  = red[0] + red[1] + red[2] + red[3];
        float b2 = red[4] + red[5] + red[6] + red[7];
        float mu = a * (1.0f / 1024.0f);
        float var = b2 * (1.0f / 1024.0f) - mu * mu;
        red[8] = mu;
        red[9] = rsqrtf(var + EPS);
    }
    __syncthreads();
    const float mu = red[8], inv = red[9], g = gamma[0];
    bf16x4 xv4 = *(const bf16x4*)(xrow + tid * 4);
    float4 r;
    r.x = (v.x - mu) * inv * g + (float)xv4[0];
    r.y = (v.y - mu) * inv * g + (float)xv4[1];
    r.z = (v.z - mu) * inv * g + (float)xv4[2];
    r.w = (v.w - mu) * inv * g + (float)xv4[3];
    r.x = r.x >= 0.f ? r.x : SLOPE * r.x;
    r.y = r.y >= 0.f ? r.y : SLOPE * r.y;
    r.z = r.z >= 0.f ? r.z : SLOPE * r.z;
    r.w = r.w >= 0.f ? r.w : SLOPE * r.w;
    ((float4*)yrow)[tid] = r;
}

extern "C" void kernel_launch(void* const* d_in, const int* in_sizes, int n_in,
                              void* d_out, int out_size, void* d_ws, size_t ws_size,
                              hipStream_t stream) {
    const float* x     = (const float*)d_in[0];
    const float* Wq    = (const float*)d_in[1];
    const float* Wk    = (const float*)d_in[2];
    const float* Wv    = (const float*)d_in[3];
    const float* Wo    = (const float*)d_in[4];
    const float* gamma = (const float*)d_in[5];
    float* y = (float*)d_out;

    char* wsb = (char*)d_ws;
    bf16* xT  = (bf16*)(wsb);                   //  8,388,608
    bf16* xB  = (bf16*)(wsb +  8388608);        //  8,388,608
    bf16* WkB = (bf16*)(wsb + 16777216);        //    262,144
    bf16* WvB = (bf16*)(wsb + 17039360);        //    262,144
    bf16* WoB = (bf16*)(wsb + 17301504);        //    262,144
    bf16* WqT = (bf16*)(wsb + 17563648);        //    262,144
    bf16* G   = (bf16*)(wsb + 17825792);        //  2,097,152
    bf16* WmT = (bf16*)(wsb + 24117248);        //  4,194,304
    bf16* Wt  = (bf16*)(wsb + 28311552);        //  2,097,152
    bf16* o   = (bf16*)(wsb + 30408704);        //  8,388,608  (end 38,797,312)

    prep_kernel<<<dim3(1440), 256, 0, stream>>>(x, Wq, Wk, Wv, Wo, xT, xB, WkB, WvB, WoB, WqT);

    // G[b] = xB[b] (x) xB[b] : [256,256], K=1024 -- 64x64 tiles, 256 blocks
    gemm64_bt<1024, bf16><<<dim3(4, 4, 16), 256, 0, stream>>>(
        xB, xB, G, 262144LL, 262144LL, 65536LL, 256);

    // tm2: per (b,h): P=Wv_h G_b (in LDS), T=(1/64) P Wk_h^T, WmT=WqT (x) T
    tm2_kernel<<<dim3(128), 256, 0, stream>>>(G, WvB, WkB, WqT, WmT);

    // Wt[b] = WoB (x) WmT[b] : [256,256], K=512 -- 64x64 tiles, 256 blocks
    gemm64_bt<512, bf16><<<dim3(4, 4, 16), 256, 0, stream>>>(
        WoB, WmT, Wt, 0LL, 131072LL, 65536LL, 256);

    // o[b] = Wt[b] (x) xT[b] : [256,1024], K=256 -- 128x128 tiles, 256 blocks
    gemm128_bt<256, bf16><<<dim3(2, 8, 16), 256, 0, stream>>>(
        Wt, xT, o, 65536LL, 262144LL, 262144LL, 1024);

    norm_kernel<<<dim3(4096), 256, 0, stream>>>(o, xB, gamma, y);
}

// Round 5
// 120.669 us; speedup vs baseline: 2.9758x; 1.0167x over previous
//
#include <hip/hip_runtime.h>

typedef __bf16 bf16;
typedef bf16 bf16x8 __attribute__((ext_vector_type(8)));
typedef bf16 bf16x4 __attribute__((ext_vector_type(4)));
typedef float f32x4 __attribute__((ext_vector_type(4)));

#define EPS 1e-5f
#define SLOPE 0.01f

// async global->LDS, 16B/lane. Invariant: lds ptr == wave-uniform base + lane*16B.
__device__ __forceinline__ void gld_lds16(const bf16* g, bf16* l) {
    __builtin_amdgcn_global_load_lds(
        (const __attribute__((address_space(1))) unsigned int*)g,
        (__attribute__((address_space(3))) unsigned int*)l, 16, 0, 0);
}

// XCD-locality remap: raw blockIdx -> (batch b, tile t) with blockIdx%8 == b%8.
// HW round-robins blockIdx->XCD, so all tiles of batch b land on XCD b%8.
// Bijective for B=16, any pow2 T (tiles per batch).
// raw = (b&7) + 8*((b>>3)*T + t)
template<int LOG2T>
__device__ __forceinline__ void xcd_decode(int raw, int& b, int& t) {
    const int p = raw & 7, m = raw >> 3;
    b = ((m >> LOG2T) << 3) + p;
    t = m & ((1 << LOG2T) - 1);
}

// ---------- prep: xT[b][l][c], xB[b][c][l], Wk/Wv/Wo bf16, WqT[h][c][e] ------
__global__ __launch_bounds__(256) void prep_kernel(
    const float* __restrict__ x,
    const float* __restrict__ Wq, const float* __restrict__ Wk,
    const float* __restrict__ Wv, const float* __restrict__ Wo,
    bf16* __restrict__ xT, bf16* __restrict__ xB,
    bf16* __restrict__ WkB, bf16* __restrict__ WvB,
    bf16* __restrict__ WoB, bf16* __restrict__ WqT)
{
    __shared__ float tile[64][65];
    const int raw = blockIdx.x;
    int id;
    if (raw < 1024) {              // xcd-swizzled: batch b -> XCD b%8
        int b, t64; xcd_decode<6>(raw, b, t64);
        id = (b << 6) | t64;
    } else id = raw;
    const int t = threadIdx.x;
    if (id < 1024) {
        const int lt = id & 15, ct = (id >> 4) & 3, b = id >> 6;
        {
            const int cl = t >> 2;            // c within tile
            const int l4 = (t & 3) << 4;      // l within tile (16-chunks)
            const float* src = x + (size_t)(b * 256 + ct * 64 + cl) * 1024 + lt * 64 + l4;
            float4 v0 = ((const float4*)src)[0];
            float4 v1 = ((const float4*)src)[1];
            float4 v2 = ((const float4*)src)[2];
            float4 v3 = ((const float4*)src)[3];
            bf16x8 r0, r1;
            r0[0]=(bf16)v0.x; r0[1]=(bf16)v0.y; r0[2]=(bf16)v0.z; r0[3]=(bf16)v0.w;
            r0[4]=(bf16)v1.x; r0[5]=(bf16)v1.y; r0[6]=(bf16)v1.z; r0[7]=(bf16)v1.w;
            r1[0]=(bf16)v2.x; r1[1]=(bf16)v2.y; r1[2]=(bf16)v2.z; r1[3]=(bf16)v2.w;
            r1[4]=(bf16)v3.x; r1[5]=(bf16)v3.y; r1[6]=(bf16)v3.z; r1[7]=(bf16)v3.w;
            bf16* xbd = xB + (size_t)(b * 256 + ct * 64 + cl) * 1024 + lt * 64 + l4;
            *(bf16x8*)xbd = r0;
            *(bf16x8*)(xbd + 8) = r1;
            float* tr = &tile[cl][l4];
            tr[0]=v0.x; tr[1]=v0.y; tr[2]=v0.z; tr[3]=v0.w;
            tr[4]=v1.x; tr[5]=v1.y; tr[6]=v1.z; tr[7]=v1.w;
            tr[8]=v2.x; tr[9]=v2.y; tr[10]=v2.z; tr[11]=v2.w;
            tr[12]=v3.x; tr[13]=v3.y; tr[14]=v3.z; tr[15]=v3.w;
        }
        __syncthreads();
        {
            const int lw = t >> 2;            // l within tile
            const int ec = (t & 3) << 4;      // c within tile
            bf16x8 o0, o1;
            #pragma unroll
            for (int ii = 0; ii < 8; ++ii) {
                o0[ii] = (bf16)tile[ec + ii][lw];
                o1[ii] = (bf16)tile[ec + 8 + ii][lw];
            }
            bf16* dst = xT + (size_t)(b * 1024 + lt * 64 + lw) * 256 + ct * 64 + ec;
            *(bf16x8*)dst = o0;
            *(bf16x8*)(dst + 8) = o1;
        }
    } else if (id < 1408) {
        // straight bf16 casts of Wk, Wv, Wo
        const int i = (id - 1024) * 1024 + t * 4;    // [0, 393216)
        const float* src; bf16* dst;
        if (i < 131072)      { src = Wk + i;            dst = WkB + i; }
        else if (i < 262144) { src = Wv + (i - 131072); dst = WvB + (i - 131072); }
        else                 { src = Wo + (i - 262144); dst = WoB + (i - 262144); }
        float4 v = *(const float4*)src;
        bf16x4 o;
        o[0]=(bf16)v.x; o[1]=(bf16)v.y; o[2]=(bf16)v.z; o[3]=(bf16)v.w;
        *(bf16x4*)dst = o;
    } else {
        // per-head transpose: WqT[h][c][e] = Wq[h*64+e][c]
        const int id2 = id - 1408;            // 0..31
        const int h = id2 >> 2, ct = id2 & 3;
        {
            const int e  = t >> 2;
            const int c4 = (t & 3) << 4;
            const float* src = Wq + (size_t)(h * 64 + e) * 256 + ct * 64 + c4;
            float4 v0 = ((const float4*)src)[0];
            float4 v1 = ((const float4*)src)[1];
            float4 v2 = ((const float4*)src)[2];
            float4 v3 = ((const float4*)src)[3];
            float* tr = &tile[e][c4];
            tr[0]=v0.x; tr[1]=v0.y; tr[2]=v0.z; tr[3]=v0.w;
            tr[4]=v1.x; tr[5]=v1.y; tr[6]=v1.z; tr[7]=v1.w;
            tr[8]=v2.x; tr[9]=v2.y; tr[10]=v2.z; tr[11]=v2.w;
            tr[12]=v3.x; tr[13]=v3.y; tr[14]=v3.z; tr[15]=v3.w;
        }
        __syncthreads();
        {
            const int c  = t >> 2;
            const int e4 = (t & 3) << 4;
            bf16x8 o0, o1;
            #pragma unroll
            for (int ii = 0; ii < 8; ++ii) {
                o0[ii] = (bf16)tile[e4 + ii][c];
                o1[ii] = (bf16)tile[e4 + 8 + ii][c];
            }
            bf16* dst = WqT + (size_t)h * 16384 + (size_t)(ct * 64 + c) * 64 + e4;
            *(bf16x8*)dst = o0;
            *(bf16x8*)(dst + 8) = o1;
        }
    }
}

// ------- 128x128-tile MFMA GEMM, B^T form: C[z] = A[z] * Bt[z]^T -------------
// 1D grid, 16 tiles/batch (2x8), XCD-swizzled. NB=5 ring, counted vmcnt.
template<int KDIM, typename OutT>
__global__ __launch_bounds__(256) void gemm128_bt(
    const bf16* __restrict__ A, const bf16* __restrict__ Bt, OutT* __restrict__ C,
    long long sA, long long sBt, long long sC, int ldC)
{
    constexpr int NT = KDIM / 32;      // K-tiles
    constexpr int NB = 5;              // LDS ring depth (4 tiles in flight)
    __shared__ bf16 As[NB][128 * 32];  // 40 KB
    __shared__ bf16 Bs[NB][128 * 32];  // 40 KB
    int z, tt; xcd_decode<4>(blockIdx.x, z, tt);
    A  += (size_t)z * sA;
    Bt += (size_t)z * sBt;
    C  += (size_t)z * sC;
    const int m0 = (tt >> 3) * 128;    // 2 M-tiles
    const int n0 = (tt & 7) * 128;     // 8 N-tiles
    const int t = threadIdx.x, w = t >> 6, l = t & 63;
    const int srow = w * 16 + (l >> 2);
    const int ske  = (l & 3) * 8;
    const bf16* ga = A  + (size_t)(m0 + srow) * KDIM + ske;
    const bf16* gb = Bt + (size_t)(n0 + srow) * KDIM + ske;
    const int loff = srow * 32 + ske;  // lane*16B within wave: gld_lds-safe
    const int lm = l & 15, lq = l >> 4;
    const int wm = (w & 1) * 64, wn = (w >> 1) * 64;

    #pragma unroll
    for (int i = 0; i < NB - 1; ++i) {
        const int k0 = i * 32;
        gld_lds16(ga + k0, &As[i][0] + loff);
        gld_lds16(ga + k0 + (size_t)64 * KDIM, &As[i][0] + 64 * 32 + loff);
        gld_lds16(gb + k0, &Bs[i][0] + loff);
        gld_lds16(gb + k0 + (size_t)64 * KDIM, &Bs[i][0] + 64 * 32 + loff);
    }

    f32x4 acc[4][4] = {};
    #pragma unroll
    for (int kt = 0; kt < NT; ++kt) {
        const int cur = kt % NB;
        const int stg = (kt + NB - 1) % NB;
        const int remain = NT - 1 - kt;
        if (remain >= 3)      asm volatile("s_waitcnt vmcnt(12)" ::: "memory");
        else if (remain == 2) asm volatile("s_waitcnt vmcnt(8)"  ::: "memory");
        else if (remain == 1) asm volatile("s_waitcnt vmcnt(4)"  ::: "memory");
        else                  asm volatile("s_waitcnt vmcnt(0)"  ::: "memory");
        __builtin_amdgcn_s_barrier();
        __builtin_amdgcn_sched_barrier(0);
        if (kt + NB - 1 < NT) {
            const int k0 = (kt + NB - 1) * 32;
            gld_lds16(ga + k0, &As[stg][0] + loff);
            gld_lds16(ga + k0 + (size_t)64 * KDIM, &As[stg][0] + 64 * 32 + loff);
            gld_lds16(gb + k0, &Bs[stg][0] + loff);
            gld_lds16(gb + k0 + (size_t)64 * KDIM, &Bs[stg][0] + 64 * 32 + loff);
        }
        bf16x8 af[4], bfr[4];
        #pragma unroll
        for (int i = 0; i < 4; ++i)
            af[i] = *(const bf16x8*)(&As[cur][0] + (wm + i * 16 + lm) * 32 + lq * 8);
        #pragma unroll
        for (int j = 0; j < 4; ++j)
            bfr[j] = *(const bf16x8*)(&Bs[cur][0] + (wn + j * 16 + lm) * 32 + lq * 8);
        #pragma unroll
        for (int i = 0; i < 4; ++i)
            #pragma unroll
            for (int j = 0; j < 4; ++j)
                acc[i][j] = __builtin_amdgcn_mfma_f32_16x16x32_bf16(af[i], bfr[j], acc[i][j], 0, 0, 0);
    }
    #pragma unroll
    for (int i = 0; i < 4; ++i)
        #pragma unroll
        for (int j = 0; j < 4; ++j) {
            const int row = m0 + wm + i * 16 + lq * 4;
            const int col = n0 + wn + j * 16 + lm;
            OutT* cp = C + (size_t)row * ldC + col;
            #pragma unroll
            for (int r = 0; r < 4; ++r)
                cp[(size_t)r * ldC] = (OutT)acc[i][j][r];
        }
}

// ------- 64x64-tile MFMA GEMM, B^T form. 1D grid, 16 tiles/batch (4x4) ------
template<int KDIM, typename OutT>
__global__ __launch_bounds__(256) void gemm64_bt(
    const bf16* __restrict__ A, const bf16* __restrict__ Bt, OutT* __restrict__ C,
    long long sA, long long sBt, long long sC, int ldC)
{
    constexpr int NT = KDIM / 32;
    constexpr int NB = 5;
    __shared__ bf16 As[NB][64 * 32];   // 20 KB
    __shared__ bf16 Bs[NB][64 * 32];   // 20 KB
    int z, tt; xcd_decode<4>(blockIdx.x, z, tt);
    A  += (size_t)z * sA;
    Bt += (size_t)z * sBt;
    C  += (size_t)z * sC;
    const int m0 = (tt & 3) * 64;
    const int n0 = (tt >> 2) * 64;
    const int t = threadIdx.x, w = t >> 6, l = t & 63;
    const int srow = t >> 2;           // 0..63
    const int ske  = (t & 3) * 8;
    const bf16* ga = A  + (size_t)(m0 + srow) * KDIM + ske;
    const bf16* gb = Bt + (size_t)(n0 + srow) * KDIM + ske;
    const int loff = srow * 32 + ske;
    const int lm = l & 15, lq = l >> 4;

    #pragma unroll
    for (int i = 0; i < NB - 1; ++i) {
        const int k0 = i * 32;
        gld_lds16(ga + k0, &As[i][0] + loff);
        gld_lds16(gb + k0, &Bs[i][0] + loff);
    }

    f32x4 acc[4] = {};
    #pragma unroll
    for (int kt = 0; kt < NT; ++kt) {
        const int cur = kt % NB;
        const int stg = (kt + NB - 1) % NB;
        const int remain = NT - 1 - kt;
        if (remain >= 3)      asm volatile("s_waitcnt vmcnt(6)" ::: "memory");
        else if (remain == 2) asm volatile("s_waitcnt vmcnt(4)" ::: "memory");
        else if (remain == 1) asm volatile("s_waitcnt vmcnt(2)" ::: "memory");
        else                  asm volatile("s_waitcnt vmcnt(0)" ::: "memory");
        __builtin_amdgcn_s_barrier();
        __builtin_amdgcn_sched_barrier(0);
        if (kt + NB - 1 < NT) {
            const int k0 = (kt + NB - 1) * 32;
            gld_lds16(ga + k0, &As[stg][0] + loff);
            gld_lds16(gb + k0, &Bs[stg][0] + loff);
        }
        bf16x8 af = *(const bf16x8*)(&As[cur][0] + (w * 16 + lm) * 32 + lq * 8);
        bf16x8 bfr[4];
        #pragma unroll
        for (int j = 0; j < 4; ++j)
            bfr[j] = *(const bf16x8*)(&Bs[cur][0] + (j * 16 + lm) * 32 + lq * 8);
        #pragma unroll
        for (int j = 0; j < 4; ++j)
            acc[j] = __builtin_amdgcn_mfma_f32_16x16x32_bf16(af, bfr[j], acc[j], 0, 0, 0);
    }
    #pragma unroll
    for (int j = 0; j < 4; ++j) {
        const int row = m0 + w * 16 + lq * 4;
        const int col = n0 + j * 16 + lm;
        OutT* cp = C + (size_t)row * ldC + col;
        #pragma unroll
        for (int r = 0; r < 4; ++r)
            cp[(size_t)r * ldC] = (OutT)acc[j][r];
    }
}

// ---- tm2 per (b,h): P = Wv_h (x) G_b (=S_h), T = (1/64) P Wk_h^T,
//      WmT_h = WqT_h (x) T_h.  S never touches global memory.
// LDS union (128 KB): phase P: {P, Va, Gr[4-ring]}; phase T/M: {P, Kc, Qb, Tb}.
struct __align__(16) Tm2Ph1 { bf16 P[16384]; bf16 Va[16384]; bf16 Gr[4][8192]; };
struct __align__(16) Tm2Ph2 { bf16 P[16384]; bf16 Kc[16384]; bf16 Qb[16384]; bf16 Tb[4096]; };
union  __align__(16) Tm2Sm  { Tm2Ph1 p1; Tm2Ph2 p2; };   // 128 KB, P aliases P

__global__ __launch_bounds__(256) void tm2_kernel(
    const bf16* __restrict__ G, const bf16* __restrict__ WvB,
    const bf16* __restrict__ WkB, const bf16* __restrict__ WqT,
    bf16* __restrict__ WmT)
{
    __shared__ Tm2Sm sm;
    int b, h; xcd_decode<3>(blockIdx.x, b, h);   // 8 heads/batch, XCD = b%8
    const bf16* Gg = G   + (size_t)b * 65536;       // [256][256]
    const bf16* Vg = WvB + (size_t)h * 16384;       // Wv_h [64][256]
    const bf16* Kg = WkB + (size_t)h * 16384;       // Wk_h [64][256]
    const bf16* Qg = WqT + (size_t)h * 16384;       // WqT_h [256][64]
    const int t = threadIdx.x, w = t >> 6, l = t & 63;
    const int lm = l & 15, lq = l >> 4;

    // ---- phase P staging: Gr t0, Va, Gr t1, Gr t2 (20 gld/thread) ----
    #pragma unroll
    for (int it = 0; it < 4; ++it) {               // tile 0
        const int idx = it * 256 + t;
        const int r = idx >> 2, s2 = idx & 3;
        gld_lds16(Gg + (size_t)r * 256 + 0 * 32 + (s2 ^ (r & 3)) * 8,
                  &sm.p1.Gr[0][0] + r * 32 + s2 * 8);
    }
    #pragma unroll
    for (int it = 0; it < 8; ++it) {               // Va
        const int idx = it * 256 + t;
        const int r = idx >> 5, s = idx & 31;
        gld_lds16(Vg + (size_t)r * 256 + (s ^ (r & 7)) * 8,
                  sm.p1.Va + r * 256 + s * 8);
    }
    #pragma unroll
    for (int tb = 1; tb < 3; ++tb) {               // tiles 1,2
        #pragma unroll
        for (int it = 0; it < 4; ++it) {
            const int idx = it * 256 + t;
            const int r = idx >> 2, s2 = idx & 3;
            gld_lds16(Gg + (size_t)r * 256 + tb * 32 + (s2 ^ (r & 3)) * 8,
                      &sm.p1.Gr[tb][0] + r * 32 + s2 * 8);
        }
    }

    // ---- phase P K-loop: P[d][c] = sum_k Wv[d,k] G[c,k], M=64 N=256 K=256 ---
    f32x4 accP[4][4] = {};
    #pragma unroll
    for (int kt = 0; kt < 8; ++kt) {
        if (kt <= 5)      asm volatile("s_waitcnt vmcnt(8)" ::: "memory");
        else if (kt == 6) asm volatile("s_waitcnt vmcnt(4)" ::: "memory");
        else              asm volatile("s_waitcnt vmcnt(0)" ::: "memory");
        __builtin_amdgcn_s_barrier();
        __builtin_amdgcn_sched_barrier(0);
        if (kt < 5) {                               // stage tile kt+3
            const int tb = kt + 3;
            #pragma unroll
            for (int it = 0; it < 4; ++it) {
                const int idx = it * 256 + t;
                const int r = idx >> 2, s2 = idx & 3;
                gld_lds16(Gg + (size_t)r * 256 + tb * 32 + (s2 ^ (r & 3)) * 8,
                          &sm.p1.Gr[tb & 3][0] + r * 32 + s2 * 8);
            }
        }
        bf16x8 af[4], bfr[4];
        #pragma unroll
        for (int mf = 0; mf < 4; ++mf) {
            const int ra = mf * 16 + lm;
            af[mf] = *(const bf16x8*)(sm.p1.Va + ra * 256 + ((kt * 4 + lq) ^ (ra & 7)) * 8);
        }
        #pragma unroll
        for (int nf = 0; nf < 4; ++nf) {
            const int rb = w * 64 + nf * 16 + lm;
            bfr[nf] = *(const bf16x8*)(&sm.p1.Gr[kt & 3][0] + rb * 32 + (lq ^ (rb & 3)) * 8);
        }
        #pragma unroll
        for (int mf = 0; mf < 4; ++mf)
            #pragma unroll
            for (int nf = 0; nf < 4; ++nf)
                accP[mf][nf] = __builtin_amdgcn_mfma_f32_16x16x32_bf16(af[mf], bfr[nf], accP[mf][nf], 0, 0, 0);
    }
    // write P (bf16, unscaled - matches old S rounding) swizzled [64][256]
    #pragma unroll
    for (int mf = 0; mf < 4; ++mf)
        #pragma unroll
        for (int nf = 0; nf < 4; ++nf)
            #pragma unroll
            for (int ri = 0; ri < 4; ++ri) {
                const int d = mf * 16 + lq * 4 + ri;
                const int c = w * 64 + nf * 16 + lm;
                sm.p1.P[d * 256 + (((c >> 3) ^ (d & 7)) << 3) + (c & 7)] =
                    (bf16)accP[mf][nf][ri];
            }
    __syncthreads();   // all waves done with Va/Gr; P published

    // ---- stage Kc (aliases Va) and Qb (aliases Gr) ----
    #pragma unroll
    for (int it = 0; it < 8; ++it) {
        const int idx = it * 256 + t;
        const int r = idx >> 5, s = idx & 31;
        gld_lds16(Kg + (size_t)r * 256 + (s ^ (r & 7)) * 8,
                  sm.p2.Kc + r * 256 + s * 8);
    }
    #pragma unroll
    for (int it = 0; it < 8; ++it) {
        const int idx = it * 256 + t;
        const int r = idx >> 3, s2 = idx & 7;
        gld_lds16(Qg + (size_t)r * 64 + (s2 ^ (r & 7)) * 8,
                  sm.p2.Qb + r * 64 + s2 * 8);
    }

    // ---- phase T: T[d][e] = (1/64) sum_c P[d,c] Wk[e,c], M=64 N=64 K=256 ----
    asm volatile("s_waitcnt vmcnt(8)" ::: "memory");   // Kc resident, Qb in flight
    __builtin_amdgcn_s_barrier();
    __builtin_amdgcn_sched_barrier(0);
    f32x4 accT[4] = {};
    #pragma unroll
    for (int kk = 0; kk < 8; ++kk) {
        const int ra = w * 16 + lm;
        bf16x8 a = *(const bf16x8*)(sm.p2.P + ra * 256 + ((kk * 4 + lq) ^ (ra & 7)) * 8);
        #pragma unroll
        for (int nf = 0; nf < 4; ++nf) {
            const int rb = nf * 16 + lm;
            bf16x8 bb = *(const bf16x8*)(sm.p2.Kc + rb * 256 + ((kk * 4 + lq) ^ (rb & 7)) * 8);
            accT[nf] = __builtin_amdgcn_mfma_f32_16x16x32_bf16(a, bb, accT[nf], 0, 0, 0);
        }
    }
    // write T (scaled 1/64) into Tb, swizzled [64][64]
    #pragma unroll
    for (int nf = 0; nf < 4; ++nf)
        #pragma unroll
        for (int ri = 0; ri < 4; ++ri) {
            const int row = w * 16 + lq * 4 + ri;
            const int col = nf * 16 + lm;
            sm.p2.Tb[row * 64 + (((col >> 3) ^ (row & 7)) << 3) + (col & 7)] =
                (bf16)(accT[nf][ri] * 0.015625f);
        }
    asm volatile("s_waitcnt vmcnt(0)" ::: "memory");   // Qb resident
    __syncthreads();                                   // Tb + Qb published

    // ---- phase M: WmT_h[c,d] = sum_e WqT_h[c,e] T_h[d,e], M=256 N=64 K=64 ---
    f32x4 accM[4][4] = {};
    #pragma unroll
    for (int ks = 0; ks < 2; ++ks) {
        const int q = ks * 4 + lq;                     // 0..7
        bf16x8 bfrag[4];
        #pragma unroll
        for (int nf = 0; nf < 4; ++nf) {
            const int rb = nf * 16 + lm;
            bfrag[nf] = *(const bf16x8*)(sm.p2.Tb + rb * 64 + (q ^ (rb & 7)) * 8);
        }
        #pragma unroll
        for (int mf = 0; mf < 4; ++mf) {
            const int ra = w * 64 + mf * 16 + lm;
            bf16x8 a = *(const bf16x8*)(sm.p2.Qb + ra * 64 + (q ^ (ra & 7)) * 8);
            #pragma unroll
            for (int nf = 0; nf < 4; ++nf)
                accM[mf][nf] = __builtin_amdgcn_mfma_f32_16x16x32_bf16(a, bfrag[nf], accM[mf][nf], 0, 0, 0);
        }
    }
    bf16* Wg = WmT + (size_t)b * 131072 + h * 64;
    #pragma unroll
    for (int mf = 0; mf < 4; ++mf)
        #pragma unroll
        for (int nf = 0; nf < 4; ++nf)
            #pragma unroll
            for (int ri = 0; ri < 4; ++ri) {
                const int c = w * 64 + mf * 16 + lq * 4 + ri;
                const int d = nf * 16 + lm;
                Wg[(size_t)c * 512 + d] = (bf16)accM[mf][nf][ri];
            }
}

// ------------- InstanceNorm over L + gamma residual + LeakyReLU --------------
__global__ __launch_bounds__(256) void norm_kernel(
    const bf16* __restrict__ o, const bf16* __restrict__ xB,
    const float* __restrict__ gamma, float* __restrict__ y)
{
    int b, c; xcd_decode<8>(blockIdx.x, b, c);   // 256 rows/batch, XCD = b%8
    const size_t row = ((size_t)b << 8) | c;
    const bf16* orow = o + row * 1024;
    const bf16* xrow = xB + row * 1024;
    float* yrow = y + row * 1024;
    const int tid = threadIdx.x;

    bf16x4 ov = *(const bf16x4*)(orow + tid * 4);
    float4 v = {(float)ov[0], (float)ov[1], (float)ov[2], (float)ov[3]};
    float s  = v.x + v.y + v.z + v.w;
    float ss = v.x * v.x + v.y * v.y + v.z * v.z + v.w * v.w;
    #pragma unroll
    for (int off = 32; off > 0; off >>= 1) {
        s  += __shfl_down(s, off);
        ss += __shfl_down(ss, off);
    }
    __shared__ float red[10];
    const int wave = tid >> 6, lane = tid & 63;
    if (lane == 0) { red[wave] = s; red[4 + wave] = ss; }
    __syncthreads();
    if (tid == 0) {
        float a  = red[0] + red[1] + red[2] + red[3];
        float b2 = red[4] + red[5] + red[6] + red[7];
        float mu = a * (1.0f / 1024.0f);
        float var = b2 * (1.0f / 1024.0f) - mu * mu;
        red[8] = mu;
        red[9] = rsqrtf(var + EPS);
    }
    __syncthreads();
    const float mu = red[8], inv = red[9], g = gamma[0];
    bf16x4 xv4 = *(const bf16x4*)(xrow + tid * 4);
    float4 r;
    r.x = (v.x - mu) * inv * g + (float)xv4[0];
    r.y = (v.y - mu) * inv * g + (float)xv4[1];
    r.z = (v.z - mu) * inv * g + (float)xv4[2];
    r.w = (v.w - mu) * inv * g + (float)xv4[3];
    r.x = r.x >= 0.f ? r.x : SLOPE * r.x;
    r.y = r.y >= 0.f ? r.y : SLOPE * r.y;
    r.z = r.z >= 0.f ? r.z : SLOPE * r.z;
    r.w = r.w >= 0.f ? r.w : SLOPE * r.w;
    ((float4*)yrow)[tid] = r;
}

extern "C" void kernel_launch(void* const* d_in, const int* in_sizes, int n_in,
                              void* d_out, int out_size, void* d_ws, size_t ws_size,
                              hipStream_t stream) {
    const float* x     = (const float*)d_in[0];
    const float* Wq    = (const float*)d_in[1];
    const float* Wk    = (const float*)d_in[2];
    const float* Wv    = (const float*)d_in[3];
    const float* Wo    = (const float*)d_in[4];
    const float* gamma = (const float*)d_in[5];
    float* y = (float*)d_out;

    char* wsb = (char*)d_ws;
    bf16* xT  = (bf16*)(wsb);                   //  8,388,608
    bf16* xB  = (bf16*)(wsb +  8388608);        //  8,388,608
    bf16* WkB = (bf16*)(wsb + 16777216);        //    262,144
    bf16* WvB = (bf16*)(wsb + 17039360);        //    262,144
    bf16* WoB = (bf16*)(wsb + 17301504);        //    262,144
    bf16* WqT = (bf16*)(wsb + 17563648);        //    262,144
    bf16* G   = (bf16*)(wsb + 17825792);        //  2,097,152
    bf16* WmT = (bf16*)(wsb + 24117248);        //  4,194,304
    bf16* Wt  = (bf16*)(wsb + 28311552);        //  2,097,152
    bf16* o   = (bf16*)(wsb + 30408704);        //  8,388,608  (end 38,797,312)

    prep_kernel<<<dim3(1440), 256, 0, stream>>>(x, Wq, Wk, Wv, Wo, xT, xB, WkB, WvB, WoB, WqT);

    // G[b] = xB[b] (x) xB[b] : [256,256], K=1024 -- 256 blocks, XCD-swizzled
    gemm64_bt<1024, bf16><<<dim3(256), 256, 0, stream>>>(
        xB, xB, G, 262144LL, 262144LL, 65536LL, 256);

    // tm2: per (b,h): P=Wv_h G_b (in LDS), T=(1/64) P Wk_h^T, WmT=WqT (x) T
    tm2_kernel<<<dim3(128), 256, 0, stream>>>(G, WvB, WkB, WqT, WmT);

    // Wt[b] = WoB (x) WmT[b] : [256,256], K=512 -- 256 blocks, XCD-swizzled
    gemm64_bt<512, bf16><<<dim3(256), 256, 0, stream>>>(
        WoB, WmT, Wt, 0LL, 131072LL, 65536LL, 256);

    // o[b] = Wt[b] (x) xT[b] : [256,1024], K=256 -- 256 blocks, XCD-swizzled
    gemm128_bt<256, bf16><<<dim3(256), 256, 0, stream>>>(
        Wt, xT, o, 65536LL, 262144LL, 262144LL, 1024);

    norm_kernel<<<dim3(4096), 256, 0, stream>>>(o, xB, gamma, y);
}

// Round 6
// 119.334 us; speedup vs baseline: 3.0091x; 1.0112x over previous
//
#include <hip/hip_runtime.h>

typedef __bf16 bf16;
typedef bf16 bf16x8 __attribute__((ext_vector_type(8)));
typedef bf16 bf16x4 __attribute__((ext_vector_type(4)));
typedef float f32x4 __attribute__((ext_vector_type(4)));

#define EPS 1e-5f
#define SLOPE 0.01f

// async global->LDS, 16B/lane. Invariant: lds ptr == wave-uniform base + lane*16B.
__device__ __forceinline__ void gld_lds16(const bf16* g, bf16* l) {
    __builtin_amdgcn_global_load_lds(
        (const __attribute__((address_space(1))) unsigned int*)g,
        (__attribute__((address_space(3))) unsigned int*)l, 16, 0, 0);
}

// XCD-locality remap: raw blockIdx -> (batch b, tile t) with blockIdx%8 == b%8.
template<int LOG2T>
__device__ __forceinline__ void xcd_decode(int raw, int& b, int& t) {
    const int p = raw & 7, m = raw >> 3;
    b = ((m >> LOG2T) << 3) + p;
    t = m & ((1 << LOG2T) - 1);
}

// ---------- prep: xT[b][l][c], xB[b][c][l], Wk/Wv/Wo bf16, WqT[h][c][e] ------
__global__ __launch_bounds__(256) void prep_kernel(
    const float* __restrict__ x,
    const float* __restrict__ Wq, const float* __restrict__ Wk,
    const float* __restrict__ Wv, const float* __restrict__ Wo,
    bf16* __restrict__ xT, bf16* __restrict__ xB,
    bf16* __restrict__ WkB, bf16* __restrict__ WvB,
    bf16* __restrict__ WoB, bf16* __restrict__ WqT)
{
    __shared__ float tile[64][65];
    const int raw = blockIdx.x;
    int id;
    if (raw < 1024) {              // xcd-swizzled: batch b -> XCD b%8
        int b, t64; xcd_decode<6>(raw, b, t64);
        id = (b << 6) | t64;
    } else id = raw;
    const int t = threadIdx.x;
    if (id < 1024) {
        const int lt = id & 15, ct = (id >> 4) & 3, b = id >> 6;
        {
            const int cl = t >> 2;            // c within tile
            const int l4 = (t & 3) << 4;      // l within tile (16-chunks)
            const float* src = x + (size_t)(b * 256 + ct * 64 + cl) * 1024 + lt * 64 + l4;
            float4 v0 = ((const float4*)src)[0];
            float4 v1 = ((const float4*)src)[1];
            float4 v2 = ((const float4*)src)[2];
            float4 v3 = ((const float4*)src)[3];
            bf16x8 r0, r1;
            r0[0]=(bf16)v0.x; r0[1]=(bf16)v0.y; r0[2]=(bf16)v0.z; r0[3]=(bf16)v0.w;
            r0[4]=(bf16)v1.x; r0[5]=(bf16)v1.y; r0[6]=(bf16)v1.z; r0[7]=(bf16)v1.w;
            r1[0]=(bf16)v2.x; r1[1]=(bf16)v2.y; r1[2]=(bf16)v2.z; r1[3]=(bf16)v2.w;
            r1[4]=(bf16)v3.x; r1[5]=(bf16)v3.y; r1[6]=(bf16)v3.z; r1[7]=(bf16)v3.w;
            bf16* xbd = xB + (size_t)(b * 256 + ct * 64 + cl) * 1024 + lt * 64 + l4;
            *(bf16x8*)xbd = r0;
            *(bf16x8*)(xbd + 8) = r1;
            float* tr = &tile[cl][l4];
            tr[0]=v0.x; tr[1]=v0.y; tr[2]=v0.z; tr[3]=v0.w;
            tr[4]=v1.x; tr[5]=v1.y; tr[6]=v1.z; tr[7]=v1.w;
            tr[8]=v2.x; tr[9]=v2.y; tr[10]=v2.z; tr[11]=v2.w;
            tr[12]=v3.x; tr[13]=v3.y; tr[14]=v3.z; tr[15]=v3.w;
        }
        __syncthreads();
        {
            const int lw = t >> 2;            // l within tile
            const int ec = (t & 3) << 4;      // c within tile
            bf16x8 o0, o1;
            #pragma unroll
            for (int ii = 0; ii < 8; ++ii) {
                o0[ii] = (bf16)tile[ec + ii][lw];
                o1[ii] = (bf16)tile[ec + 8 + ii][lw];
            }
            bf16* dst = xT + (size_t)(b * 1024 + lt * 64 + lw) * 256 + ct * 64 + ec;
            *(bf16x8*)dst = o0;
            *(bf16x8*)(dst + 8) = o1;
        }
    } else if (id < 1408) {
        // straight bf16 casts of Wk, Wv, Wo
        const int i = (id - 1024) * 1024 + t * 4;    // [0, 393216)
        const float* src; bf16* dst;
        if (i < 131072)      { src = Wk + i;            dst = WkB + i; }
        else if (i < 262144) { src = Wv + (i - 131072); dst = WvB + (i - 131072); }
        else                 { src = Wo + (i - 262144); dst = WoB + (i - 262144); }
        float4 v = *(const float4*)src;
        bf16x4 o;
        o[0]=(bf16)v.x; o[1]=(bf16)v.y; o[2]=(bf16)v.z; o[3]=(bf16)v.w;
        *(bf16x4*)dst = o;
    } else {
        // per-head transpose: WqT[h][c][e] = Wq[h*64+e][c]
        const int id2 = id - 1408;            // 0..31
        const int h = id2 >> 2, ct = id2 & 3;
        {
            const int e  = t >> 2;
            const int c4 = (t & 3) << 4;
            const float* src = Wq + (size_t)(h * 64 + e) * 256 + ct * 64 + c4;
            float4 v0 = ((const float4*)src)[0];
            float4 v1 = ((const float4*)src)[1];
            float4 v2 = ((const float4*)src)[2];
            float4 v3 = ((const float4*)src)[3];
            float* tr = &tile[e][c4];
            tr[0]=v0.x; tr[1]=v0.y; tr[2]=v0.z; tr[3]=v0.w;
            tr[4]=v1.x; tr[5]=v1.y; tr[6]=v1.z; tr[7]=v1.w;
            tr[8]=v2.x; tr[9]=v2.y; tr[10]=v2.z; tr[11]=v2.w;
            tr[12]=v3.x; tr[13]=v3.y; tr[14]=v3.z; tr[15]=v3.w;
        }
        __syncthreads();
        {
            const int c  = t >> 2;
            const int e4 = (t & 3) << 4;
            bf16x8 o0, o1;
            #pragma unroll
            for (int ii = 0; ii < 8; ++ii) {
                o0[ii] = (bf16)tile[e4 + ii][c];
                o1[ii] = (bf16)tile[e4 + 8 + ii][c];
            }
            bf16* dst = WqT + (size_t)h * 16384 + (size_t)(ct * 64 + c) * 64 + e4;
            *(bf16x8*)dst = o0;
            *(bf16x8*)(dst + 8) = o1;
        }
    }
}

// ------- 128x128-tile MFMA GEMM, B^T form: C[z] = A[z] * Bt[z]^T -------------
// 1D grid, 16 tiles/batch (2x8), XCD-swizzled. NB=5 ring, counted vmcnt.
template<int KDIM, typename OutT>
__global__ __launch_bounds__(256) void gemm128_bt(
    const bf16* __restrict__ A, const bf16* __restrict__ Bt, OutT* __restrict__ C,
    long long sA, long long sBt, long long sC, int ldC)
{
    constexpr int NT = KDIM / 32;      // K-tiles
    constexpr int NB = 5;              // LDS ring depth (4 tiles in flight)
    __shared__ bf16 As[NB][128 * 32];  // 40 KB
    __shared__ bf16 Bs[NB][128 * 32];  // 40 KB
    int z, tt; xcd_decode<4>(blockIdx.x, z, tt);
    A  += (size_t)z * sA;
    Bt += (size_t)z * sBt;
    C  += (size_t)z * sC;
    const int m0 = (tt >> 3) * 128;    // 2 M-tiles
    const int n0 = (tt & 7) * 128;     // 8 N-tiles
    const int t = threadIdx.x, w = t >> 6, l = t & 63;
    const int srow = w * 16 + (l >> 2);
    const int ske  = (l & 3) * 8;
    const bf16* ga = A  + (size_t)(m0 + srow) * KDIM + ske;
    const bf16* gb = Bt + (size_t)(n0 + srow) * KDIM + ske;
    const int loff = srow * 32 + ske;  // lane*16B within wave: gld_lds-safe
    const int lm = l & 15, lq = l >> 4;
    const int wm = (w & 1) * 64, wn = (w >> 1) * 64;

    #pragma unroll
    for (int i = 0; i < NB - 1; ++i) {
        const int k0 = i * 32;
        gld_lds16(ga + k0, &As[i][0] + loff);
        gld_lds16(ga + k0 + (size_t)64 * KDIM, &As[i][0] + 64 * 32 + loff);
        gld_lds16(gb + k0, &Bs[i][0] + loff);
        gld_lds16(gb + k0 + (size_t)64 * KDIM, &Bs[i][0] + 64 * 32 + loff);
    }

    f32x4 acc[4][4] = {};
    #pragma unroll
    for (int kt = 0; kt < NT; ++kt) {
        const int cur = kt % NB;
        const int stg = (kt + NB - 1) % NB;
        const int remain = NT - 1 - kt;
        if (remain >= 3)      asm volatile("s_waitcnt vmcnt(12)" ::: "memory");
        else if (remain == 2) asm volatile("s_waitcnt vmcnt(8)"  ::: "memory");
        else if (remain == 1) asm volatile("s_waitcnt vmcnt(4)"  ::: "memory");
        else                  asm volatile("s_waitcnt vmcnt(0)"  ::: "memory");
        __builtin_amdgcn_s_barrier();
        __builtin_amdgcn_sched_barrier(0);
        if (kt + NB - 1 < NT) {
            const int k0 = (kt + NB - 1) * 32;
            gld_lds16(ga + k0, &As[stg][0] + loff);
            gld_lds16(ga + k0 + (size_t)64 * KDIM, &As[stg][0] + 64 * 32 + loff);
            gld_lds16(gb + k0, &Bs[stg][0] + loff);
            gld_lds16(gb + k0 + (size_t)64 * KDIM, &Bs[stg][0] + 64 * 32 + loff);
        }
        bf16x8 af[4], bfr[4];
        #pragma unroll
        for (int i = 0; i < 4; ++i)
            af[i] = *(const bf16x8*)(&As[cur][0] + (wm + i * 16 + lm) * 32 + lq * 8);
        #pragma unroll
        for (int j = 0; j < 4; ++j)
            bfr[j] = *(const bf16x8*)(&Bs[cur][0] + (wn + j * 16 + lm) * 32 + lq * 8);
        #pragma unroll
        for (int i = 0; i < 4; ++i)
            #pragma unroll
            for (int j = 0; j < 4; ++j)
                acc[i][j] = __builtin_amdgcn_mfma_f32_16x16x32_bf16(af[i], bfr[j], acc[i][j], 0, 0, 0);
    }
    #pragma unroll
    for (int i = 0; i < 4; ++i)
        #pragma unroll
        for (int j = 0; j < 4; ++j) {
            const int row = m0 + wm + i * 16 + lq * 4;
            const int col = n0 + wn + j * 16 + lm;
            OutT* cp = C + (size_t)row * ldC + col;
            #pragma unroll
            for (int r = 0; r < 4; ++r)
                cp[(size_t)r * ldC] = (OutT)acc[i][j][r];
        }
}

// ------- 64x64-tile MFMA GEMM, B^T form. 1D grid, 16 tiles/batch (4x4) ------
template<int KDIM, typename OutT>
__global__ __launch_bounds__(256) void gemm64_bt(
    const bf16* __restrict__ A, const bf16* __restrict__ Bt, OutT* __restrict__ C,
    long long sA, long long sBt, long long sC, int ldC)
{
    constexpr int NT = KDIM / 32;
    constexpr int NB = 5;
    __shared__ bf16 As[NB][64 * 32];   // 20 KB
    __shared__ bf16 Bs[NB][64 * 32];   // 20 KB
    int z, tt; xcd_decode<4>(blockIdx.x, z, tt);
    A  += (size_t)z * sA;
    Bt += (size_t)z * sBt;
    C  += (size_t)z * sC;
    const int m0 = (tt & 3) * 64;
    const int n0 = (tt >> 2) * 64;
    const int t = threadIdx.x, w = t >> 6, l = t & 63;
    const int srow = t >> 2;           // 0..63
    const int ske  = (t & 3) * 8;
    const bf16* ga = A  + (size_t)(m0 + srow) * KDIM + ske;
    const bf16* gb = Bt + (size_t)(n0 + srow) * KDIM + ske;
    const int loff = srow * 32 + ske;
    const int lm = l & 15, lq = l >> 4;

    #pragma unroll
    for (int i = 0; i < NB - 1; ++i) {
        const int k0 = i * 32;
        gld_lds16(ga + k0, &As[i][0] + loff);
        gld_lds16(gb + k0, &Bs[i][0] + loff);
    }

    f32x4 acc[4] = {};
    #pragma unroll
    for (int kt = 0; kt < NT; ++kt) {
        const int cur = kt % NB;
        const int stg = (kt + NB - 1) % NB;
        const int remain = NT - 1 - kt;
        if (remain >= 3)      asm volatile("s_waitcnt vmcnt(6)" ::: "memory");
        else if (remain == 2) asm volatile("s_waitcnt vmcnt(4)" ::: "memory");
        else if (remain == 1) asm volatile("s_waitcnt vmcnt(2)" ::: "memory");
        else                  asm volatile("s_waitcnt vmcnt(0)" ::: "memory");
        __builtin_amdgcn_s_barrier();
        __builtin_amdgcn_sched_barrier(0);
        if (kt + NB - 1 < NT) {
            const int k0 = (kt + NB - 1) * 32;
            gld_lds16(ga + k0, &As[stg][0] + loff);
            gld_lds16(gb + k0, &Bs[stg][0] + loff);
        }
        bf16x8 af = *(const bf16x8*)(&As[cur][0] + (w * 16 + lm) * 32 + lq * 8);
        bf16x8 bfr[4];
        #pragma unroll
        for (int j = 0; j < 4; ++j)
            bfr[j] = *(const bf16x8*)(&Bs[cur][0] + (j * 16 + lm) * 32 + lq * 8);
        #pragma unroll
        for (int j = 0; j < 4; ++j)
            acc[j] = __builtin_amdgcn_mfma_f32_16x16x32_bf16(af, bfr[j], acc[j], 0, 0, 0);
    }
    #pragma unroll
    for (int j = 0; j < 4; ++j) {
        const int row = m0 + w * 16 + lq * 4;
        const int col = n0 + j * 16 + lm;
        OutT* cp = C + (size_t)row * ldC + col;
        #pragma unroll
        for (int r = 0; r < 4; ++r)
            cp[(size_t)r * ldC] = (OutT)acc[j][r];
    }
}

// ---- tm2 per (b,h,half): d-split of the P->T->M pipeline, 256 blocks -------
// P_half[d',c] = sum_k Wv_h[half*32+d',k] G_b[c,k]   (M=32, N=256, K=256)
// T_half[d',e] = (1/64) sum_c P_half[d',c] Wk_h[e,c] (M=32, N=64,  K=256)
// WmT[c][h*64 + half*32 + d'] = sum_e WqT_h[c,e] T_half[d',e]
// LDS union (96 KB): phase P: {P, Va, Gr[4-ring]}; phase T/M: {P, Kc, Qb, Tb}.
struct __align__(16) Tm2Ph1 { bf16 P[8192]; bf16 Va[8192]; bf16 Gr[4][8192]; };
struct __align__(16) Tm2Ph2 { bf16 P[8192]; bf16 Kc[16384]; bf16 Qb[16384]; bf16 Tb[2048]; };
union  __align__(16) Tm2Sm  { Tm2Ph1 p1; Tm2Ph2 p2; };   // 96 KB, P aliases P

__global__ __launch_bounds__(256) void tm2_kernel(
    const bf16* __restrict__ G, const bf16* __restrict__ WvB,
    const bf16* __restrict__ WkB, const bf16* __restrict__ WqT,
    bf16* __restrict__ WmT)
{
    __shared__ Tm2Sm sm;
    int b, tt; xcd_decode<4>(blockIdx.x, b, tt);   // 16 tiles/batch, XCD = b%8
    const int h = tt >> 1, half = tt & 1;
    const bf16* Gg = G   + (size_t)b * 65536;       // [256][256]
    const bf16* Vg = WvB + (size_t)h * 16384 + half * 32 * 256;  // Wv_h rows half*32..+31
    const bf16* Kg = WkB + (size_t)h * 16384;       // Wk_h [64][256]
    const bf16* Qg = WqT + (size_t)h * 16384;       // WqT_h [256][64]
    const int t = threadIdx.x, w = t >> 6, l = t & 63;
    const int lm = l & 15, lq = l >> 4;

    // ---- phase P staging: Gr t0 (4), Va (4), Gr t1, t2 (8) = 16 gld/thread --
    #pragma unroll
    for (int it = 0; it < 4; ++it) {               // G tile 0 [256 c][32 k]
        const int idx = it * 256 + t;
        const int r = idx >> 2, s2 = idx & 3;
        gld_lds16(Gg + (size_t)r * 256 + 0 * 32 + (s2 ^ (r & 3)) * 8,
                  &sm.p1.Gr[0][0] + r * 32 + s2 * 8);
    }
    #pragma unroll
    for (int it = 0; it < 4; ++it) {               // Va [32][256]
        const int idx = it * 256 + t;
        const int r = idx >> 5, s = idx & 31;
        gld_lds16(Vg + (size_t)r * 256 + (s ^ (r & 7)) * 8,
                  sm.p1.Va + r * 256 + s * 8);
    }
    #pragma unroll
    for (int tb = 1; tb < 3; ++tb) {               // G tiles 1,2
        #pragma unroll
        for (int it = 0; it < 4; ++it) {
            const int idx = it * 256 + t;
            const int r = idx >> 2, s2 = idx & 3;
            gld_lds16(Gg + (size_t)r * 256 + tb * 32 + (s2 ^ (r & 3)) * 8,
                      &sm.p1.Gr[tb][0] + r * 32 + s2 * 8);
        }
    }

    // ---- phase P K-loop: 8 steps, 3-deep G ring, counted vmcnt -------------
    f32x4 accP[2][4] = {};
    #pragma unroll
    for (int kt = 0; kt < 8; ++kt) {
        if (kt <= 5)      asm volatile("s_waitcnt vmcnt(8)" ::: "memory");
        else if (kt == 6) asm volatile("s_waitcnt vmcnt(4)" ::: "memory");
        else              asm volatile("s_waitcnt vmcnt(0)" ::: "memory");
        __builtin_amdgcn_s_barrier();
        __builtin_amdgcn_sched_barrier(0);
        if (kt < 5) {                               // stage G tile kt+3
            const int tb = kt + 3;
            #pragma unroll
            for (int it = 0; it < 4; ++it) {
                const int idx = it * 256 + t;
                const int r = idx >> 2, s2 = idx & 3;
                gld_lds16(Gg + (size_t)r * 256 + tb * 32 + (s2 ^ (r & 3)) * 8,
                          &sm.p1.Gr[tb & 3][0] + r * 32 + s2 * 8);
            }
        }
        bf16x8 af[2], bfr[4];
        #pragma unroll
        for (int mf = 0; mf < 2; ++mf) {
            const int ra = mf * 16 + lm;
            af[mf] = *(const bf16x8*)(sm.p1.Va + ra * 256 + ((kt * 4 + lq) ^ (ra & 7)) * 8);
        }
        #pragma unroll
        for (int nf = 0; nf < 4; ++nf) {
            const int rb = w * 64 + nf * 16 + lm;
            bfr[nf] = *(const bf16x8*)(&sm.p1.Gr[kt & 3][0] + rb * 32 + (lq ^ (rb & 3)) * 8);
        }
        #pragma unroll
        for (int mf = 0; mf < 2; ++mf)
            #pragma unroll
            for (int nf = 0; nf < 4; ++nf)
                accP[mf][nf] = __builtin_amdgcn_mfma_f32_16x16x32_bf16(af[mf], bfr[nf], accP[mf][nf], 0, 0, 0);
    }
    // write P_half (bf16, unscaled - matches old S rounding) swizzled [32][256]
    #pragma unroll
    for (int mf = 0; mf < 2; ++mf)
        #pragma unroll
        for (int nf = 0; nf < 4; ++nf)
            #pragma unroll
            for (int ri = 0; ri < 4; ++ri) {
                const int d = mf * 16 + lq * 4 + ri;        // 0..31
                const int c = w * 64 + nf * 16 + lm;
                sm.p1.P[d * 256 + (((c >> 3) ^ (d & 7)) << 3) + (c & 7)] =
                    (bf16)accP[mf][nf][ri];
            }
    __syncthreads();   // all waves done with Va/Gr; P published

    // ---- stage Kc (aliases Va..) and Qb (aliases Gr) ----
    #pragma unroll
    for (int it = 0; it < 8; ++it) {
        const int idx = it * 256 + t;
        const int r = idx >> 5, s = idx & 31;
        gld_lds16(Kg + (size_t)r * 256 + (s ^ (r & 7)) * 8,
                  sm.p2.Kc + r * 256 + s * 8);
    }
    #pragma unroll
    for (int it = 0; it < 8; ++it) {
        const int idx = it * 256 + t;
        const int r = idx >> 3, s2 = idx & 7;
        gld_lds16(Qg + (size_t)r * 64 + (s2 ^ (r & 7)) * 8,
                  sm.p2.Qb + r * 64 + s2 * 8);
    }

    // ---- phase T: M=32 (mf loop), N=64 (wave-split), K=256 ------------------
    asm volatile("s_waitcnt vmcnt(8)" ::: "memory");   // Kc resident, Qb in flight
    __builtin_amdgcn_s_barrier();
    __builtin_amdgcn_sched_barrier(0);
    f32x4 accT[2] = {};
    #pragma unroll
    for (int kk = 0; kk < 8; ++kk) {
        const int rb = w * 16 + lm;                      // e-frag = wave
        bf16x8 bb = *(const bf16x8*)(sm.p2.Kc + rb * 256 + ((kk * 4 + lq) ^ (rb & 7)) * 8);
        #pragma unroll
        for (int mf = 0; mf < 2; ++mf) {
            const int ra = mf * 16 + lm;
            bf16x8 a = *(const bf16x8*)(sm.p2.P + ra * 256 + ((kk * 4 + lq) ^ (ra & 7)) * 8);
            accT[mf] = __builtin_amdgcn_mfma_f32_16x16x32_bf16(a, bb, accT[mf], 0, 0, 0);
        }
    }
    // write T_half (scaled 1/64) into Tb, swizzled [32][64]
    #pragma unroll
    for (int mf = 0; mf < 2; ++mf)
        #pragma unroll
        for (int ri = 0; ri < 4; ++ri) {
            const int row = mf * 16 + lq * 4 + ri;       // 0..31
            const int col = w * 16 + lm;                 // 0..63
            sm.p2.Tb[row * 64 + (((col >> 3) ^ (row & 7)) << 3) + (col & 7)] =
                (bf16)(accT[mf][ri] * 0.015625f);
        }
    asm volatile("s_waitcnt vmcnt(0)" ::: "memory");   // Qb resident
    __syncthreads();                                   // Tb + Qb published

    // ---- phase M: M=256 (wave*64 + mf), N=32 (nf<2), K=64 -------------------
    f32x4 accM[4][2] = {};
    #pragma unroll
    for (int ks = 0; ks < 2; ++ks) {
        const int q = ks * 4 + lq;                     // 0..7
        bf16x8 bfrag[2];
        #pragma unroll
        for (int nf = 0; nf < 2; ++nf) {
            const int rb = nf * 16 + lm;               // 0..31
            bfrag[nf] = *(const bf16x8*)(sm.p2.Tb + rb * 64 + (q ^ (rb & 7)) * 8);
        }
        #pragma unroll
        for (int mf = 0; mf < 4; ++mf) {
            const int ra = w * 64 + mf * 16 + lm;
            bf16x8 a = *(const bf16x8*)(sm.p2.Qb + ra * 64 + (q ^ (ra & 7)) * 8);
            #pragma unroll
            for (int nf = 0; nf < 2; ++nf)
                accM[mf][nf] = __builtin_amdgcn_mfma_f32_16x16x32_bf16(a, bfrag[nf], accM[mf][nf], 0, 0, 0);
        }
    }
    bf16* Wg = WmT + (size_t)b * 131072 + h * 64 + half * 32;
    #pragma unroll
    for (int mf = 0; mf < 4; ++mf)
        #pragma unroll
        for (int nf = 0; nf < 2; ++nf)
            #pragma unroll
            for (int ri = 0; ri < 4; ++ri) {
                const int c = w * 64 + mf * 16 + lq * 4 + ri;
                const int d = nf * 16 + lm;            // 0..31 within half
                Wg[(size_t)c * 512 + d] = (bf16)accM[mf][nf][ri];
            }
}

// ------------- InstanceNorm over L + gamma residual + LeakyReLU --------------
// 2 rows/block, 8 elems/thread (16B bf16x8 loads, 2x float4 stores).
__global__ __launch_bounds__(256) void norm_kernel(
    const bf16* __restrict__ o, const bf16* __restrict__ xB,
    const float* __restrict__ gamma, float* __restrict__ y)
{
    int b, rp; xcd_decode<7>(blockIdx.x, b, rp);  // 128 row-pairs/batch, XCD=b%8
    const int tid = threadIdx.x;
    const int w2 = tid >> 7;                      // row of the pair (waves 0,1 | 2,3)
    const int ti = tid & 127;                     // thread within row
    const size_t row = ((size_t)b << 8) | (rp * 2 + w2);
    const bf16* orow = o + row * 1024;
    const bf16* xrow = xB + row * 1024;
    float* yrow = y + row * 1024;

    bf16x8 ov = *(const bf16x8*)(orow + ti * 8);
    float v[8];
    float s = 0.f, ss = 0.f;
    #pragma unroll
    for (int i = 0; i < 8; ++i) {
        v[i] = (float)ov[i];
        s += v[i]; ss += v[i] * v[i];
    }
    #pragma unroll
    for (int off = 32; off > 0; off >>= 1) {
        s  += __shfl_down(s, off);
        ss += __shfl_down(ss, off);
    }
    __shared__ float red[8];
    const int wave = tid >> 6, lane = tid & 63;
    if (lane == 0) { red[wave] = s; red[4 + wave] = ss; }
    __syncthreads();
    const float a  = red[w2 * 2] + red[w2 * 2 + 1];
    const float b2 = red[4 + w2 * 2] + red[4 + w2 * 2 + 1];
    const float mu = a * (1.0f / 1024.0f);
    const float var = b2 * (1.0f / 1024.0f) - mu * mu;
    const float inv = rsqrtf(var + EPS);
    const float g = gamma[0];

    bf16x8 xv = *(const bf16x8*)(xrow + ti * 8);
    float r[8];
    #pragma unroll
    for (int i = 0; i < 8; ++i) {
        float rr = (v[i] - mu) * inv * g + (float)xv[i];
        r[i] = rr >= 0.f ? rr : SLOPE * rr;
    }
    float4 r0 = {r[0], r[1], r[2], r[3]};
    float4 r1 = {r[4], r[5], r[6], r[7]};
    ((float4*)(yrow + ti * 8))[0] = r0;
    ((float4*)(yrow + ti * 8 + 4))[0] = r1;
}

extern "C" void kernel_launch(void* const* d_in, const int* in_sizes, int n_in,
                              void* d_out, int out_size, void* d_ws, size_t ws_size,
                              hipStream_t stream) {
    const float* x     = (const float*)d_in[0];
    const float* Wq    = (const float*)d_in[1];
    const float* Wk    = (const float*)d_in[2];
    const float* Wv    = (const float*)d_in[3];
    const float* Wo    = (const float*)d_in[4];
    const float* gamma = (const float*)d_in[5];
    float* y = (float*)d_out;

    char* wsb = (char*)d_ws;
    bf16* xT  = (bf16*)(wsb);                   //  8,388,608
    bf16* xB  = (bf16*)(wsb +  8388608);        //  8,388,608
    bf16* WkB = (bf16*)(wsb + 16777216);        //    262,144
    bf16* WvB = (bf16*)(wsb + 17039360);        //    262,144
    bf16* WoB = (bf16*)(wsb + 17301504);        //    262,144
    bf16* WqT = (bf16*)(wsb + 17563648);        //    262,144
    bf16* G   = (bf16*)(wsb + 17825792);        //  2,097,152
    bf16* WmT = (bf16*)(wsb + 24117248);        //  4,194,304
    bf16* Wt  = (bf16*)(wsb + 28311552);        //  2,097,152
    bf16* o   = (bf16*)(wsb + 30408704);        //  8,388,608  (end 38,797,312)

    prep_kernel<<<dim3(1440), 256, 0, stream>>>(x, Wq, Wk, Wv, Wo, xT, xB, WkB, WvB, WoB, WqT);

    // G[b] = xB[b] (x) xB[b] : [256,256], K=1024 -- 256 blocks, XCD-swizzled
    gemm64_bt<1024, bf16><<<dim3(256), 256, 0, stream>>>(
        xB, xB, G, 262144LL, 262144LL, 65536LL, 256);

    // tm2: per (b,h,half): P=Wv_half G_b (LDS), T=(1/64) P Wk^T, WmT=WqT (x) T
    tm2_kernel<<<dim3(256), 256, 0, stream>>>(G, WvB, WkB, WqT, WmT);

    // Wt[b] = WoB (x) WmT[b] : [256,256], K=512 -- 256 blocks, XCD-swizzled
    gemm64_bt<512, bf16><<<dim3(256), 256, 0, stream>>>(
        WoB, WmT, Wt, 0LL, 131072LL, 65536LL, 256);

    // o[b] = Wt[b] (x) xT[b] : [256,1024], K=256 -- 256 blocks, XCD-swizzled
    gemm128_bt<256, bf16><<<dim3(256), 256, 0, stream>>>(
        Wt, xT, o, 65536LL, 262144LL, 262144LL, 1024);

    norm_kernel<<<dim3(2048), 256, 0, stream>>>(o, xB, gamma, y);
}